// Round 2
// baseline (1185.759 us; speedup 1.0000x reference)
//
#include <hip/hip_runtime.h>
#include <math.h>

#define NTOT  65536
#define NEDGE 524288
#define BGR   128
#define NPG   512
#define NL    32
#define F1    128
#define F2    96
#define F3    64
#define KT    16
#define BINS  16
#define BN    32

typedef unsigned short bf;

// ---------------- helpers ----------------
__device__ __forceinline__ float b2f(bf v) { return __uint_as_float(((unsigned)v) << 16); }
__device__ __forceinline__ bf f2b(float f) {
    unsigned u = __float_as_uint(f);
    return (bf)((u + 0x7FFF + ((u >> 16) & 1)) >> 16);  // RNE
}
__device__ __forceinline__ unsigned encf(float f) {
    unsigned u = __float_as_uint(f);
    return (u & 0x80000000u) ? ~u : (u | 0x80000000u);
}
__device__ __forceinline__ float decf(unsigned e) {
    unsigned u = (e & 0x80000000u) ? (e ^ 0x80000000u) : ~e;
    return __uint_as_float(u);
}

// ---------------- init ----------------
__global__ __launch_bounds__(256) void fill_k(unsigned* __restrict__ p, unsigned v, int n) {
    int i = blockIdx.x * 256 + threadIdx.x;
    if (i < n) p[i] = v;
}

// ---------------- CSR build ----------------
__global__ __launch_bounds__(256) void deg_k(const int* __restrict__ dst, int* __restrict__ deg) {
    int e = blockIdx.x * 256 + threadIdx.x;
    atomicAdd(&deg[dst[e]], 1);
}

__global__ __launch_bounds__(256) void dinv_k(const int* __restrict__ deg, float* __restrict__ dinv) {
    int n = blockIdx.x * 256 + threadIdx.x;
    dinv[n] = 1.0f / sqrtf((float)deg[n] + 1.0f);
}

__global__ __launch_bounds__(256) void scan1_k(const int* __restrict__ deg, int* __restrict__ off, int* __restrict__ bsum) {
    __shared__ int s[256];
    int t = threadIdx.x, b = blockIdx.x, i = b * 256 + t;
    int x = deg[i];
    s[t] = x;
    __syncthreads();
    for (int o = 1; o < 256; o <<= 1) {
        int v = (t >= o) ? s[t - o] : 0;
        __syncthreads();
        s[t] += v;
        __syncthreads();
    }
    off[i] = s[t] - x;
    if (t == 255) bsum[b] = s[255];
}

__global__ __launch_bounds__(256) void scan2_k(int* __restrict__ bsum) {
    __shared__ int s[256];
    int t = threadIdx.x;
    int x = bsum[t];
    s[t] = x;
    __syncthreads();
    for (int o = 1; o < 256; o <<= 1) {
        int v = (t >= o) ? s[t - o] : 0;
        __syncthreads();
        s[t] += v;
        __syncthreads();
    }
    bsum[t] = s[t] - x;  // exclusive
}

__global__ __launch_bounds__(256) void scan3_k(int* __restrict__ off, const int* __restrict__ bsum) {
    int i = blockIdx.x * 256 + threadIdx.x;
    off[i] += bsum[i >> 8];
    if (i == 0) off[NTOT] = NEDGE;
}

__global__ __launch_bounds__(256) void scatter_k(const int* __restrict__ src, const int* __restrict__ dst,
                                                 const int* __restrict__ off, int* __restrict__ cur,
                                                 const float* __restrict__ dinv,
                                                 int* __restrict__ csrc, float* __restrict__ cnorm) {
    int e = blockIdx.x * 256 + threadIdx.x;
    int s = src[e], d = dst[e];
    int p = atomicAdd(&cur[d], 1);
    int idx = off[d] + p;
    csrc[idx] = s;
    cnorm[idx] = dinv[s] * dinv[d];
}

// ---------------- GEMM: out[NT x COUT](bf16) = X[NT x CIN](bf16) @ W(fp32) ----------------
template <int CIN, int COUT, int BIAS, int RELU>
__global__ __launch_bounds__(256) void gemm_k(const bf* __restrict__ X, const float* __restrict__ Wm,
                                              const float* __restrict__ bias, bf* __restrict__ out) {
    constexpr int C4 = COUT / 4;
    int t = blockIdx.x * 256 + threadIdx.x;
    int row = t / C4;
    int c = (t % C4) * 4;
    const bf* xr = X + (size_t)row * CIN;
    float ax = 0.f, ay = 0.f, az = 0.f, aw = 0.f;
#pragma unroll 2
    for (int k = 0; k < CIN; k += 4) {
        ushort4 xv = *(const ushort4*)(xr + k);
        float a0 = b2f(xv.x), a1 = b2f(xv.y), a2 = b2f(xv.z), a3 = b2f(xv.w);
        float4 w0 = *(const float4*)(Wm + (size_t)(k + 0) * COUT + c);
        float4 w1 = *(const float4*)(Wm + (size_t)(k + 1) * COUT + c);
        float4 w2 = *(const float4*)(Wm + (size_t)(k + 2) * COUT + c);
        float4 w3 = *(const float4*)(Wm + (size_t)(k + 3) * COUT + c);
        ax += a0 * w0.x + a1 * w1.x + a2 * w2.x + a3 * w3.x;
        ay += a0 * w0.y + a1 * w1.y + a2 * w2.y + a3 * w3.y;
        az += a0 * w0.z + a1 * w1.z + a2 * w2.z + a3 * w3.z;
        aw += a0 * w0.w + a1 * w1.w + a2 * w2.w + a3 * w3.w;
    }
    if (BIAS) {
        float4 bv = *(const float4*)(bias + c);
        ax += bv.x; ay += bv.y; az += bv.z; aw += bv.w;
    }
    if (RELU) {
        ax = fmaxf(ax, 0.f); ay = fmaxf(ay, 0.f); az = fmaxf(az, 0.f); aw = fmaxf(aw, 0.f);
    }
    ushort4 o;
    o.x = f2b(ax); o.y = f2b(ay); o.z = f2b(az); o.w = f2b(aw);
    *(ushort4*)(out + (size_t)row * COUT + c) = o;
}

// ---------------- GCN aggregation (gather via CSR), bf16 or fp32 input -> bf16 out -------
template <int C, int BIAS, int RELU, int FIN32>
__global__ __launch_bounds__(256) void agg_k(const void* __restrict__ hin_, const float* __restrict__ bias,
                                             const int* __restrict__ off, const int* __restrict__ esrc,
                                             const float* __restrict__ enorm, const float* __restrict__ dinv,
                                             bf* __restrict__ out) {
    constexpr int C4 = C / 4;
    int t = blockIdx.x * 256 + threadIdx.x;
    int node = t / C4;
    int c = (t % C4) * 4;
    float d = dinv[node];
    float sc = d * d;
    float ax, ay, az, aw;
    if (FIN32) {
        const float* hin = (const float*)hin_;
        float4 h = *(const float4*)(hin + (size_t)node * C + c);
        ax = h.x * sc; ay = h.y * sc; az = h.z * sc; aw = h.w * sc;
    } else {
        const bf* hin = (const bf*)hin_;
        ushort4 h = *(const ushort4*)(hin + (size_t)node * C + c);
        ax = b2f(h.x) * sc; ay = b2f(h.y) * sc; az = b2f(h.z) * sc; aw = b2f(h.w) * sc;
    }
    int e0 = off[node], e1 = off[node + 1];
    for (int j = e0; j < e1; j++) {
        int s = esrc[j];
        float w = enorm[j];
        if (FIN32) {
            const float* hin = (const float*)hin_;
            float4 hs = *(const float4*)(hin + (size_t)s * C + c);
            ax += w * hs.x; ay += w * hs.y; az += w * hs.z; aw += w * hs.w;
        } else {
            const bf* hin = (const bf*)hin_;
            ushort4 hs = *(const ushort4*)(hin + (size_t)s * C + c);
            ax += w * b2f(hs.x); ay += w * b2f(hs.y); az += w * b2f(hs.z); aw += w * b2f(hs.w);
        }
    }
    if (BIAS) {
        float4 bv = *(const float4*)(bias + c);
        ax += bv.x; ay += bv.y; az += bv.z; aw += bv.w;
    }
    if (RELU) {
        ax = fmaxf(ax, 0.f); ay = fmaxf(ay, 0.f); az = fmaxf(az, 0.f); aw = fmaxf(aw, 0.f);
    }
    ushort4 o;
    o.x = f2b(ax); o.y = f2b(ay); o.z = f2b(az); o.w = f2b(aw);
    *(ushort4*)(out + (size_t)node * C + c) = o;
}

// ---------------- similarity tiles ----------------
// block: one (graph b, 64x64 tile). 256 threads, each a 4x4 register tile.
__device__ __forceinline__ void sim_load_compute(const bf* __restrict__ f1, const bf* __restrict__ f2,
                                                 float* La, float* Lb, float acc[4][4]) {
    int bid = blockIdx.x;
    int b = bid >> 6, tile = bid & 63, tn = tile >> 3, tm = tile & 7;
    const bf* A = f1 + ((size_t)b * NPG + tn * 64) * F3;
    const bf* Bp = f2 + ((size_t)b * NPG + tm * 64) * F3;
    int t = threadIdx.x;
#pragma unroll
    for (int i = 0; i < 4; i++) {
        int idx = t + i * 256;
        int r = idx >> 4, q = (idx & 15) * 4;
        ushort4 va = *(const ushort4*)(A + r * 64 + q);
        La[r * 65 + q + 0] = b2f(va.x); La[r * 65 + q + 1] = b2f(va.y);
        La[r * 65 + q + 2] = b2f(va.z); La[r * 65 + q + 3] = b2f(va.w);
        ushort4 vb = *(const ushort4*)(Bp + r * 64 + q);
        Lb[r * 65 + q + 0] = b2f(vb.x); Lb[r * 65 + q + 1] = b2f(vb.y);
        Lb[r * 65 + q + 2] = b2f(vb.z); Lb[r * 65 + q + 3] = b2f(vb.w);
    }
    __syncthreads();
    int n0 = (t >> 4) * 4, m0 = (t & 15) * 4;
#pragma unroll 4
    for (int k = 0; k < 64; k++) {
        float a0 = La[(n0 + 0) * 65 + k], a1 = La[(n0 + 1) * 65 + k];
        float a2 = La[(n0 + 2) * 65 + k], a3 = La[(n0 + 3) * 65 + k];
        float b0 = Lb[(m0 + 0) * 65 + k], b1 = Lb[(m0 + 1) * 65 + k];
        float b2 = Lb[(m0 + 2) * 65 + k], b3 = Lb[(m0 + 3) * 65 + k];
        acc[0][0] += a0 * b0; acc[0][1] += a0 * b1; acc[0][2] += a0 * b2; acc[0][3] += a0 * b3;
        acc[1][0] += a1 * b0; acc[1][1] += a1 * b1; acc[1][2] += a1 * b2; acc[1][3] += a1 * b3;
        acc[2][0] += a2 * b0; acc[2][1] += a2 * b1; acc[2][2] += a2 * b2; acc[2][3] += a2 * b3;
        acc[3][0] += a3 * b0; acc[3][1] += a3 * b1; acc[3][2] += a3 * b2; acc[3][3] += a3 * b3;
    }
}

__global__ __launch_bounds__(256) void sim_minmax_k(const bf* __restrict__ f1, const bf* __restrict__ f2,
                                                    unsigned* __restrict__ smin, unsigned* __restrict__ smax) {
    __shared__ float La[64 * 65];
    __shared__ float Lb[64 * 65];
    float acc[4][4] = {};
    sim_load_compute(f1, f2, La, Lb, acc);
    int b = blockIdx.x >> 6;
    float mn = acc[0][0], mx = acc[0][0];
#pragma unroll
    for (int i = 0; i < 4; i++)
#pragma unroll
        for (int j = 0; j < 4; j++) {
            mn = fminf(mn, acc[i][j]);
            mx = fmaxf(mx, acc[i][j]);
        }
    for (int o = 32; o; o >>= 1) {
        mn = fminf(mn, __shfl_down(mn, o));
        mx = fmaxf(mx, __shfl_down(mx, o));
    }
    if ((threadIdx.x & 63) == 0) {
        atomicMin(&smin[b], encf(mn));
        atomicMax(&smax[b], encf(mx));
    }
}

__global__ __launch_bounds__(256) void sim_hist_k(const bf* __restrict__ f1, const bf* __restrict__ f2,
                                                  const unsigned* __restrict__ smin, const unsigned* __restrict__ smax,
                                                  int* __restrict__ hist) {
    __shared__ float La[64 * 65];
    __shared__ float Lb[64 * 65];
    __shared__ int hloc[BINS];
    if (threadIdx.x < BINS) hloc[threadIdx.x] = 0;
    float acc[4][4] = {};
    sim_load_compute(f1, f2, La, Lb, acc);  // __syncthreads inside covers hloc init
    int b = blockIdx.x >> 6;
    float vmin = 1.f / (1.f + expf(-decf(smin[b])));
    float vmax = 1.f / (1.f + expf(-decf(smax[b])));
    float width = (vmax - vmin) / (float)BINS;
    float safe = width > 0.f ? width : 1.0f;
    float inv = 1.0f / safe;
#pragma unroll
    for (int i = 0; i < 4; i++)
#pragma unroll
        for (int j = 0; j < 4; j++) {
            float v = 1.f / (1.f + expf(-acc[i][j]));
            int bi = (int)floorf((v - vmin) * inv);
            bi = bi < 0 ? 0 : (bi > BINS - 1 ? BINS - 1 : bi);
            atomicAdd(&hloc[bi], 1);
        }
    __syncthreads();
    if (threadIdx.x < BINS) atomicAdd(&hist[b * BINS + threadIdx.x], hloc[threadIdx.x]);
}

// ---------------- attention pool ----------------
__global__ __launch_bounds__(256) void pool_k(const bf* __restrict__ x, const float* __restrict__ w,
                                              float* __restrict__ out, float scale) {
    int b = blockIdx.x, t = threadIdx.x;
    int f = t & 63, g = t >> 6;
    float acc = 0.f;
    for (int r = g; r < NPG; r += 4) {
        int n = b * NPG + r;
        float c = w ? w[n] : 1.0f;
        acc += c * b2f(x[(size_t)n * F3 + f]);
    }
    __shared__ float red[256];
    red[t] = acc;
    __syncthreads();
    if (g == 0) {
        float s = red[f] + red[64 + f] + red[128 + f] + red[192 + f];
        out[b * F3 + f] = s * scale;
    }
}

__global__ void ctx_k(const float* __restrict__ mean, const float* __restrict__ Watt, float* __restrict__ ctx) {
    int b = blockIdx.x, j = threadIdx.x;  // 64 threads
    float acc = 0.f;
#pragma unroll 8
    for (int i = 0; i < F3; i++) acc += mean[b * F3 + i] * Watt[i * F3 + j];
    ctx[b * F3 + j] = tanhf(acc);
}

// one wave per node: lane = feature
__global__ __launch_bounds__(256) void coef_k(const bf* __restrict__ x, const float* __restrict__ ctx,
                                              float* __restrict__ coef) {
    int t = blockIdx.x * 256 + threadIdx.x;
    int n = t >> 6;
    int f = t & 63;
    int b = n >> 9;  // N = 512
    float v = b2f(x[(size_t)n * F3 + f]) * ctx[b * F3 + f];
    for (int o = 32; o; o >>= 1) v += __shfl_down(v, o);
    if (f == 0) coef[n] = 1.f / (1.f + expf(-v));
}

// ---------------- tensor network + tail MLP ----------------
__global__ __launch_bounds__(256) void final_k(const float* __restrict__ p1, const float* __restrict__ p2,
                                               const float* __restrict__ Wt, const float* __restrict__ Wtb,
                                               const float* __restrict__ tb, const int* __restrict__ hist,
                                               const float* __restrict__ W1, const float* __restrict__ b1,
                                               const float* __restrict__ Ws, const float* __restrict__ bs,
                                               float* __restrict__ out) {
    int b = blockIdx.x, t = threadIdx.x;
    __shared__ float cat[128];
    __shared__ float sacc[256];
    __shared__ float feat[32];
    __shared__ float hb[32];
    if (t < 64) cat[t] = p1[b * F3 + t];
    else if (t < 128) cat[t] = p2[b * F3 + (t - 64)];
    __syncthreads();
    int k = t & 15, c = t >> 4;
    float acc = 0.f;
    for (int q = 0; q < 256; q++) {
        int ij = c * 256 + q;
        int i = ij >> 6, j = ij & 63;
        acc += cat[i] * cat[64 + j] * Wt[ij * KT + k];
    }
    sacc[t] = acc;
    __syncthreads();
    if (t < KT) {
        float sc = 0.f;
        for (int c2 = 0; c2 < 16; c2++) sc += sacc[c2 * 16 + t];
        float bt = 0.f;
        for (int i = 0; i < 128; i++) bt += cat[i] * Wtb[t * 128 + i];
        float tv = sc + bt + tb[t];
        feat[t] = tv > 0.f ? tv : 0.f;
        feat[KT + t] = (float)hist[b * BINS + t] * (1.0f / (float)(NPG * NPG));
    }
    __syncthreads();
    if (t < BN) {
        float a = 0.f;
        for (int i = 0; i < KT + BINS; i++) a += feat[i] * W1[i * BN + t];
        a += b1[t];
        hb[t] = a > 0.f ? a : 0.f;
    }
    __syncthreads();
    if (t == 0) {
        float s = bs[0];
        for (int j = 0; j < BN; j++) s += hb[j] * Ws[j];
        out[b] = 1.f / (1.f + expf(-s));
    }
}

// ---------------- launch ----------------
extern "C" void kernel_launch(void* const* d_in, const int* in_sizes, int n_in,
                              void* d_out, int out_size, void* d_ws, size_t ws_size,
                              hipStream_t stream) {
    const float* x1   = (const float*)d_in[0];
    const float* x2   = (const float*)d_in[1];
    const int*   ei1  = (const int*)d_in[2];
    const int*   ei2  = (const int*)d_in[3];
    const float* Wc1  = (const float*)d_in[6];
    const float* bc1  = (const float*)d_in[7];
    const float* Wc2  = (const float*)d_in[8];
    const float* bc2  = (const float*)d_in[9];
    const float* Wc3  = (const float*)d_in[10];
    const float* bc3  = (const float*)d_in[11];
    const float* Watt = (const float*)d_in[12];
    const float* Wt   = (const float*)d_in[13];
    const float* Wtb  = (const float*)d_in[14];
    const float* tb   = (const float*)d_in[15];
    const float* W1   = (const float*)d_in[16];
    const float* b1   = (const float*)d_in[17];
    const float* Ws   = (const float*)d_in[18];
    const float* bs   = (const float*)d_in[19];
    float* out = (float*)d_out;

    // ---- workspace layout (total ~= 49.5 MB) ----
    char* wsb = (char*)d_ws;
    size_t o = 0;
    auto alloc = [&](size_t bytes) -> void* {
        void* p = wsb + o;
        o = (o + bytes + 255) & ~(size_t)255;
        return p;
    };
    bf* f1b  = (bf*)alloc((size_t)NTOT * F3 * 2);   //  8 MB
    bf* f2b  = (bf*)alloc((size_t)NTOT * F3 * 2);   //  8 MB
    bf* X    = (bf*)alloc((size_t)NTOT * F1 * 2);   // 16 MB (h1, h2)
    bf* Y    = (bf*)alloc((size_t)NTOT * F2 * 2);   // 12 MB (z1, t2, t3)
    int* off   = (int*)alloc((size_t)(NTOT + 1) * 4);
    int* csrc  = (int*)alloc((size_t)NEDGE * 4);    // 2 MB
    float* cnorm = (float*)alloc((size_t)NEDGE * 4);// 2 MB
    int* deg   = (int*)alloc((size_t)NTOT * 4);
    float* dinv = (float*)alloc((size_t)NTOT * 4);
    int* cur   = (int*)alloc((size_t)NTOT * 4);
    int* bsum  = (int*)alloc(1024);
    unsigned* smin = (unsigned*)alloc(BGR * 4);
    unsigned* smax = (unsigned*)alloc(BGR * 4);
    int* histc = (int*)alloc((size_t)BGR * BINS * 4);
    float* mean = (float*)alloc((size_t)BGR * F3 * 4);
    float* ctx  = (float*)alloc((size_t)BGR * F3 * 4);
    float* pool1 = (float*)alloc((size_t)BGR * F3 * 4);
    float* pool2 = (float*)alloc((size_t)BGR * F3 * 4);
    float* coef = (float*)alloc((size_t)NTOT * 4);
    (void)ws_size; (void)in_sizes; (void)n_in; (void)out_size;

    // global one-time inits (all via kernels; ws is poisoned before every call)
    fill_k<<<1, 256, 0, stream>>>(smin, 0xFFFFFFFFu, BGR);
    fill_k<<<1, 256, 0, stream>>>(smax, 0u, BGR);
    fill_k<<<(BGR * BINS + 255) / 256, 256, 0, stream>>>((unsigned*)histc, 0u, BGR * BINS);

    const int* eis[2] = {ei1, ei2};
    const float* xs[2] = {x1, x2};
    bf* fs[2] = {f1b, f2b};

    for (int s = 0; s < 2; s++) {
        const int* esrc = eis[s];
        const int* edst = eis[s] + NEDGE;
        fill_k<<<NTOT / 256, 256, 0, stream>>>((unsigned*)deg, 0u, NTOT);
        fill_k<<<NTOT / 256, 256, 0, stream>>>((unsigned*)cur, 0u, NTOT);
        deg_k<<<NEDGE / 256, 256, 0, stream>>>(edst, deg);
        dinv_k<<<NTOT / 256, 256, 0, stream>>>(deg, dinv);
        scan1_k<<<NTOT / 256, 256, 0, stream>>>(deg, off, bsum);
        scan2_k<<<1, 256, 0, stream>>>(bsum);
        scan3_k<<<NTOT / 256, 256, 0, stream>>>(off, bsum);
        scatter_k<<<NEDGE / 256, 256, 0, stream>>>(esrc, edst, off, cur, dinv, csrc, cnorm);

        // z1 = A_hat x  (fp32 in, bf16 out, width NL) -> Y
        agg_k<NL, 0, 0, 1><<<(NTOT * (NL / 4)) / 256, 256, 0, stream>>>(xs[s], nullptr, off, csrc, cnorm, dinv, Y);
        // h1 = relu(z1 Wc1 + bc1) -> X       [A_hat(xW) == (A_hat x)W by linearity]
        gemm_k<NL, F1, 1, 1><<<(NTOT * (F1 / 4)) / 256, 256, 0, stream>>>(Y, Wc1, bc1, X);
        // t2 = h1 Wc2 -> Y
        gemm_k<F1, F2, 0, 0><<<(NTOT * (F2 / 4)) / 256, 256, 0, stream>>>(X, Wc2, nullptr, Y);
        // h2 = relu(A_hat t2 + bc2) -> X
        agg_k<F2, 1, 1, 0><<<(NTOT * (F2 / 4)) / 256, 256, 0, stream>>>(Y, bc2, off, csrc, cnorm, dinv, X);
        // t3 = h2 Wc3 -> Y
        gemm_k<F2, F3, 0, 0><<<(NTOT * (F3 / 4)) / 256, 256, 0, stream>>>(X, Wc3, nullptr, Y);
        // f = A_hat t3 + bc3 -> fs[s]
        agg_k<F3, 1, 0, 0><<<(NTOT * (F3 / 4)) / 256, 256, 0, stream>>>(Y, bc3, off, csrc, cnorm, dinv, fs[s]);
    }

    // histogram similarity: 2 passes (minmax over raw scores, then binning)
    sim_minmax_k<<<BGR * 64, 256, 0, stream>>>(f1b, f2b, smin, smax);
    sim_hist_k<<<BGR * 64, 256, 0, stream>>>(f1b, f2b, smin, smax, histc);

    // attention pooling (sequential per side; mean/ctx/coef reused)
    float* pools[2] = {pool1, pool2};
    for (int s = 0; s < 2; s++) {
        pool_k<<<BGR, 256, 0, stream>>>(fs[s], nullptr, mean, 1.0f / (float)NPG);
        ctx_k<<<BGR, 64, 0, stream>>>(mean, Watt, ctx);
        coef_k<<<(NTOT * 64) / 256, 256, 0, stream>>>(fs[s], ctx, coef);
        pool_k<<<BGR, 256, 0, stream>>>(fs[s], coef, pools[s], 1.0f);
    }

    // tensor network + MLP tail
    final_k<<<BGR, 256, 0, stream>>>(pool1, pool2, Wt, Wtb, tb, histc, W1, b1, Ws, bs, out);
}

// Round 3
// 1062.489 us; speedup vs baseline: 1.1160x; 1.1160x over previous
//
#include <hip/hip_runtime.h>
#include <math.h>

#define NTOT  65536
#define NEDGE 524288
#define BGR   128
#define NPG   512
#define NL    32
#define F1    128
#define F2    96
#define F3    64
#define KT    16
#define BINS  16
#define BN    32

typedef unsigned short bf;
typedef __attribute__((ext_vector_type(8))) short sv8;    // 8 bf16 fragment (4 VGPRs)
typedef __attribute__((ext_vector_type(16))) float fv16;  // 32x32 mfma accumulator

// ---------------- helpers ----------------
__device__ __forceinline__ float b2f(bf v) { return __uint_as_float(((unsigned)v) << 16); }
__device__ __forceinline__ bf f2b(float f) {
    unsigned u = __float_as_uint(f);
    return (bf)((u + 0x7FFF + ((u >> 16) & 1)) >> 16);  // RNE
}
__device__ __forceinline__ unsigned encf(float f) {
    unsigned u = __float_as_uint(f);
    return (u & 0x80000000u) ? ~u : (u | 0x80000000u);
}
__device__ __forceinline__ float decf(unsigned e) {
    unsigned u = (e & 0x80000000u) ? (e ^ 0x80000000u) : ~e;
    return __uint_as_float(u);
}
__device__ __forceinline__ float sigm(float x) { return 1.f / (1.f + expf(-x)); }

// ---------------- init ----------------
__global__ __launch_bounds__(256) void fillz_k(unsigned* __restrict__ p, int n) {
    int i = blockIdx.x * 256 + threadIdx.x;
    if (i < n) p[i] = 0u;
}
// zero hist (BGR*BINS), smin=0xFFFFFFFF (BGR), smax=0 (BGR)
__global__ __launch_bounds__(256) void fill_init_k(int* __restrict__ hist, unsigned* __restrict__ smin,
                                                   unsigned* __restrict__ smax) {
    int i = blockIdx.x * 256 + threadIdx.x;
    if (i < BGR * BINS) hist[i] = 0;
    else if (i < BGR * BINS + BGR) smin[i - BGR * BINS] = 0xFFFFFFFFu;
    else if (i < BGR * BINS + 2 * BGR) smax[i - BGR * BINS - BGR] = 0u;
}

// ---------------- CSR build (batched: blockIdx.y / blockIdx.x = side) ----------------
__global__ __launch_bounds__(256) void deg_k(const int* __restrict__ ei1, const int* __restrict__ ei2,
                                             int* __restrict__ deg) {
    int side = blockIdx.y;
    const int* dst = (side ? ei2 : ei1) + NEDGE;
    int e = blockIdx.x * 256 + threadIdx.x;
    atomicAdd(&deg[(size_t)side * NTOT + dst[e]], 1);
}

__global__ __launch_bounds__(256) void dinv_k(const int* __restrict__ deg, float* __restrict__ dinv) {
    int side = blockIdx.y;
    int n = side * NTOT + blockIdx.x * 256 + threadIdx.x;
    dinv[n] = 1.0f / sqrtf((float)deg[n] + 1.0f);
}

__global__ __launch_bounds__(256) void scan1_k(const int* __restrict__ deg, int* __restrict__ off, int* __restrict__ bsum) {
    __shared__ int s[256];
    int side = blockIdx.y;
    int t = threadIdx.x, b = blockIdx.x, i = b * 256 + t;
    int x = deg[side * NTOT + i];
    s[t] = x;
    __syncthreads();
    for (int o = 1; o < 256; o <<= 1) {
        int v = (t >= o) ? s[t - o] : 0;
        __syncthreads();
        s[t] += v;
        __syncthreads();
    }
    off[side * (NTOT + 1) + i] = s[t] - x;
    if (t == 255) bsum[side * 256 + b] = s[255];
}

__global__ __launch_bounds__(256) void scan2_k(int* __restrict__ bsum) {
    __shared__ int s[256];
    int side = blockIdx.x;
    int t = threadIdx.x;
    int x = bsum[side * 256 + t];
    s[t] = x;
    __syncthreads();
    for (int o = 1; o < 256; o <<= 1) {
        int v = (t >= o) ? s[t - o] : 0;
        __syncthreads();
        s[t] += v;
        __syncthreads();
    }
    bsum[side * 256 + t] = s[t] - x;  // exclusive
}

__global__ __launch_bounds__(256) void scan3_k(int* __restrict__ off, const int* __restrict__ bsum) {
    int side = blockIdx.y;
    int i = blockIdx.x * 256 + threadIdx.x;
    off[side * (NTOT + 1) + i] += bsum[side * 256 + (i >> 8)];
    if (i == 0) off[side * (NTOT + 1) + NTOT] = NEDGE;
}

__global__ __launch_bounds__(256) void scatter_k(const int* __restrict__ ei1, const int* __restrict__ ei2,
                                                 const int* __restrict__ off, int* __restrict__ cur,
                                                 const float* __restrict__ dinv,
                                                 int* __restrict__ csrc, float* __restrict__ cnorm) {
    int side = blockIdx.y;
    const int* src = side ? ei2 : ei1;
    const int* dst = src + NEDGE;
    int e = blockIdx.x * 256 + threadIdx.x;
    int s = src[e], d = dst[e];
    int p = atomicAdd(&cur[(size_t)side * NTOT + d], 1);
    int idx = off[side * (NTOT + 1) + d] + p;
    csrc[(size_t)side * NEDGE + idx] = s;
    cnorm[(size_t)side * NEDGE + idx] = dinv[side * NTOT + s] * dinv[side * NTOT + d];
}

// ---------------- GEMM: out[NT x COUT](bf16) = X[NT x CIN](bf16) @ W(fp32) ----------------
template <int CIN, int COUT, int BIAS, int RELU>
__global__ __launch_bounds__(256) void gemm_k(const bf* __restrict__ X, const float* __restrict__ Wm,
                                              const float* __restrict__ bias, bf* __restrict__ out) {
    constexpr int C4 = COUT / 4;
    int t = blockIdx.x * 256 + threadIdx.x;
    int row = t / C4;
    int c = (t % C4) * 4;
    const bf* xr = X + (size_t)row * CIN;
    float ax = 0.f, ay = 0.f, az = 0.f, aw = 0.f;
#pragma unroll 2
    for (int k = 0; k < CIN; k += 4) {
        ushort4 xv = *(const ushort4*)(xr + k);
        float a0 = b2f(xv.x), a1 = b2f(xv.y), a2 = b2f(xv.z), a3 = b2f(xv.w);
        float4 w0 = *(const float4*)(Wm + (size_t)(k + 0) * COUT + c);
        float4 w1 = *(const float4*)(Wm + (size_t)(k + 1) * COUT + c);
        float4 w2 = *(const float4*)(Wm + (size_t)(k + 2) * COUT + c);
        float4 w3 = *(const float4*)(Wm + (size_t)(k + 3) * COUT + c);
        ax += a0 * w0.x + a1 * w1.x + a2 * w2.x + a3 * w3.x;
        ay += a0 * w0.y + a1 * w1.y + a2 * w2.y + a3 * w3.y;
        az += a0 * w0.z + a1 * w1.z + a2 * w2.z + a3 * w3.z;
        aw += a0 * w0.w + a1 * w1.w + a2 * w2.w + a3 * w3.w;
    }
    if (BIAS) {
        float4 bv = *(const float4*)(bias + c);
        ax += bv.x; ay += bv.y; az += bv.z; aw += bv.w;
    }
    if (RELU) {
        ax = fmaxf(ax, 0.f); ay = fmaxf(ay, 0.f); az = fmaxf(az, 0.f); aw = fmaxf(aw, 0.f);
    }
    ushort4 o;
    o.x = f2b(ax); o.y = f2b(ay); o.z = f2b(az); o.w = f2b(aw);
    *(ushort4*)(out + (size_t)row * COUT + c) = o;
}

// ---------------- GCN aggregation (gather via CSR), bf16 or fp32 input -> bf16 out -------
template <int C, int BIAS, int RELU, int FIN32>
__global__ __launch_bounds__(256) void agg_k(const void* __restrict__ hin_, const float* __restrict__ bias,
                                             const int* __restrict__ off, const int* __restrict__ esrc,
                                             const float* __restrict__ enorm, const float* __restrict__ dinv,
                                             bf* __restrict__ out) {
    constexpr int C4 = C / 4;
    int t = blockIdx.x * 256 + threadIdx.x;
    int node = t / C4;
    int c = (t % C4) * 4;
    float d = dinv[node];
    float sc = d * d;
    float ax, ay, az, aw;
    if (FIN32) {
        const float* hin = (const float*)hin_;
        float4 h = *(const float4*)(hin + (size_t)node * C + c);
        ax = h.x * sc; ay = h.y * sc; az = h.z * sc; aw = h.w * sc;
    } else {
        const bf* hin = (const bf*)hin_;
        ushort4 h = *(const ushort4*)(hin + (size_t)node * C + c);
        ax = b2f(h.x) * sc; ay = b2f(h.y) * sc; az = b2f(h.z) * sc; aw = b2f(h.w) * sc;
    }
    int e0 = off[node], e1 = off[node + 1];
    for (int j = e0; j < e1; j++) {
        int s = esrc[j];
        float w = enorm[j];
        if (FIN32) {
            const float* hin = (const float*)hin_;
            float4 hs = *(const float4*)(hin + (size_t)s * C + c);
            ax += w * hs.x; ay += w * hs.y; az += w * hs.z; aw += w * hs.w;
        } else {
            const bf* hin = (const bf*)hin_;
            ushort4 hs = *(const ushort4*)(hin + (size_t)s * C + c);
            ax += w * b2f(hs.x); ay += w * b2f(hs.y); az += w * b2f(hs.z); aw += w * b2f(hs.w);
        }
    }
    if (BIAS) {
        float4 bv = *(const float4*)(bias + c);
        ax += bv.x; ay += bv.y; az += bv.z; aw += bv.w;
    }
    if (RELU) {
        ax = fmaxf(ax, 0.f); ay = fmaxf(ay, 0.f); az = fmaxf(az, 0.f); aw = fmaxf(aw, 0.f);
    }
    ushort4 o;
    o.x = f2b(ax); o.y = f2b(ay); o.z = f2b(az); o.w = f2b(aw);
    *(ushort4*)(out + (size_t)node * C + c) = o;
}

// ---------------- MFMA similarity ----------------
// grid = BGR * 16 * 4 blocks; block = 4 waves; wave computes one 32x32 tile of
// S = f1_g @ f2_g^T (K=64) via 4x v_mfma_f32_32x32x16_bf16. Fragments are 8
// contiguous bf16 per lane -> direct 16B global loads, no LDS staging.
__device__ __forceinline__ int sim_mfma(const bf* __restrict__ f1, const bf* __restrict__ f2, fv16& acc) {
    int bid = blockIdx.x;
    int g = bid >> 6;
    int mt = (bid >> 2) & 15, ng = bid & 3;
    int wave = threadIdx.x >> 6, lane = threadIdx.x & 63;
    int nt = ng * 4 + wave;
    int half = lane >> 5, r = lane & 31;
    const bf* Ap = f1 + ((size_t)g * NPG + mt * 32 + r) * F3 + half * 8;
    const bf* Bp = f2 + ((size_t)g * NPG + nt * 32 + r) * F3 + half * 8;
#pragma unroll
    for (int i = 0; i < 16; i++) acc[i] = 0.f;
#pragma unroll
    for (int ks = 0; ks < 4; ks++) {
        sv8 a = *(const sv8*)(Ap + ks * 16);
        sv8 b = *(const sv8*)(Bp + ks * 16);
        acc = __builtin_amdgcn_mfma_f32_32x32x16_bf16(a, b, acc, 0, 0, 0);
    }
    return g;
}

__global__ __launch_bounds__(256) void simm_k(const bf* __restrict__ f1, const bf* __restrict__ f2,
                                              unsigned* __restrict__ smin, unsigned* __restrict__ smax) {
    fv16 acc;
    int g = sim_mfma(f1, f2, acc);
    float mn = acc[0], mx = acc[0];
#pragma unroll
    for (int i = 1; i < 16; i++) {
        mn = fminf(mn, acc[i]);
        mx = fmaxf(mx, acc[i]);
    }
    for (int o = 32; o; o >>= 1) {
        mn = fminf(mn, __shfl_down(mn, o));
        mx = fmaxf(mx, __shfl_down(mx, o));
    }
    if ((threadIdx.x & 63) == 0) {
        atomicMin(&smin[g], encf(mn));
        atomicMax(&smax[g], encf(mx));
    }
}

__global__ __launch_bounds__(256) void simh_k(const bf* __restrict__ f1, const bf* __restrict__ f2,
                                              const unsigned* __restrict__ smin, const unsigned* __restrict__ smax,
                                              int* __restrict__ hist) {
    __shared__ int hl[4][BINS];  // per-wave replicas
    int t = threadIdx.x;
    if (t < 64) hl[t >> 4][t & 15] = 0;
    __syncthreads();
    fv16 acc;
    int g = sim_mfma(f1, f2, acc);
    int wave = t >> 6;
    float vmin = sigm(decf(smin[g]));
    float vmax = sigm(decf(smax[g]));
    float width = (vmax - vmin) / (float)BINS;
    float inv = 1.0f / (width > 0.f ? width : 1.0f);
#pragma unroll
    for (int i = 0; i < 16; i++) {
        float v = sigm(acc[i]);
        int bi = (int)floorf((v - vmin) * inv);
        bi = bi < 0 ? 0 : (bi > BINS - 1 ? BINS - 1 : bi);
        atomicAdd(&hl[wave][bi], 1);
    }
    __syncthreads();
    if (t < BINS) {
        int s = hl[0][t] + hl[1][t] + hl[2][t] + hl[3][t];
        atomicAdd(&hist[g * BINS + t], s);
    }
}

// ---------------- attention pool (batched over sides via blockIdx.y) ----------------
__global__ __launch_bounds__(256) void pool_k(const bf* __restrict__ f1, const bf* __restrict__ f2,
                                              const float* __restrict__ wbase,
                                              float* __restrict__ outbase, float scale) {
    int side = blockIdx.y;
    const bf* x = side ? f2 : f1;
    const float* w = wbase ? wbase + (size_t)side * NTOT : nullptr;
    float* out = outbase + (size_t)side * BGR * F3;
    int b = blockIdx.x, t = threadIdx.x;
    int f = t & 63, gq = t >> 6;
    float acc = 0.f;
    for (int r = gq; r < NPG; r += 4) {
        int n = b * NPG + r;
        float c = w ? w[n] : 1.0f;
        acc += c * b2f(x[(size_t)n * F3 + f]);
    }
    __shared__ float red[256];
    red[t] = acc;
    __syncthreads();
    if (gq == 0) {
        float s = red[f] + red[64 + f] + red[128 + f] + red[192 + f];
        out[b * F3 + f] = s * scale;
    }
}

__global__ void ctx_k(const float* __restrict__ meanb, const float* __restrict__ Watt, float* __restrict__ ctxb) {
    int side = blockIdx.y;
    const float* mean = meanb + (size_t)side * BGR * F3;
    float* ctx = ctxb + (size_t)side * BGR * F3;
    int b = blockIdx.x, j = threadIdx.x;  // 64 threads
    float acc = 0.f;
#pragma unroll 8
    for (int i = 0; i < F3; i++) acc += mean[b * F3 + i] * Watt[i * F3 + j];
    ctx[b * F3 + j] = tanhf(acc);
}

__global__ __launch_bounds__(256) void coef_k(const bf* __restrict__ f1, const bf* __restrict__ f2,
                                              const float* __restrict__ ctxb, float* __restrict__ coefb) {
    int side = blockIdx.y;
    const bf* x = side ? f2 : f1;
    const float* ctx = ctxb + (size_t)side * BGR * F3;
    float* coef = coefb + (size_t)side * NTOT;
    int t = blockIdx.x * 256 + threadIdx.x;
    int n = t >> 6;
    int f = t & 63;
    int b = n >> 9;  // N = 512
    float v = b2f(x[(size_t)n * F3 + f]) * ctx[b * F3 + f];
    for (int o = 32; o; o >>= 1) v += __shfl_down(v, o);
    if (f == 0) coef[n] = sigm(v);
}

// ---------------- tensor network + tail MLP ----------------
__global__ __launch_bounds__(256) void final_k(const float* __restrict__ pools,
                                               const float* __restrict__ Wt, const float* __restrict__ Wtb,
                                               const float* __restrict__ tb, const int* __restrict__ hist,
                                               const float* __restrict__ W1, const float* __restrict__ b1,
                                               const float* __restrict__ Ws, const float* __restrict__ bs,
                                               float* __restrict__ out) {
    const float* p1 = pools;
    const float* p2 = pools + (size_t)BGR * F3;
    int b = blockIdx.x, t = threadIdx.x;
    __shared__ float cat[128];
    __shared__ float sacc[256];
    __shared__ float feat[32];
    __shared__ float hb[32];
    if (t < 64) cat[t] = p1[b * F3 + t];
    else if (t < 128) cat[t] = p2[b * F3 + (t - 64)];
    __syncthreads();
    int k = t & 15, c = t >> 4;
    float acc = 0.f;
    for (int q = 0; q < 256; q++) {
        int ij = c * 256 + q;
        int i = ij >> 6, j = ij & 63;
        acc += cat[i] * cat[64 + j] * Wt[ij * KT + k];
    }
    sacc[t] = acc;
    __syncthreads();
    if (t < KT) {
        float sc = 0.f;
        for (int c2 = 0; c2 < 16; c2++) sc += sacc[c2 * 16 + t];
        float bt = 0.f;
        for (int i = 0; i < 128; i++) bt += cat[i] * Wtb[t * 128 + i];
        float tv = sc + bt + tb[t];
        feat[t] = tv > 0.f ? tv : 0.f;
        feat[KT + t] = (float)hist[b * BINS + t] * (1.0f / (float)(NPG * NPG));
    }
    __syncthreads();
    if (t < BN) {
        float a = 0.f;
        for (int i = 0; i < KT + BINS; i++) a += feat[i] * W1[i * BN + t];
        a += b1[t];
        hb[t] = a > 0.f ? a : 0.f;
    }
    __syncthreads();
    if (t == 0) {
        float s = bs[0];
        for (int j = 0; j < BN; j++) s += hb[j] * Ws[j];
        out[b] = sigm(s);
    }
}

// ---------------- launch ----------------
extern "C" void kernel_launch(void* const* d_in, const int* in_sizes, int n_in,
                              void* d_out, int out_size, void* d_ws, size_t ws_size,
                              hipStream_t stream) {
    const float* x1   = (const float*)d_in[0];
    const float* x2   = (const float*)d_in[1];
    const int*   ei1  = (const int*)d_in[2];
    const int*   ei2  = (const int*)d_in[3];
    const float* Wc1  = (const float*)d_in[6];
    const float* bc1  = (const float*)d_in[7];
    const float* Wc2  = (const float*)d_in[8];
    const float* bc2  = (const float*)d_in[9];
    const float* Wc3  = (const float*)d_in[10];
    const float* bc3  = (const float*)d_in[11];
    const float* Watt = (const float*)d_in[12];
    const float* Wt   = (const float*)d_in[13];
    const float* Wtb  = (const float*)d_in[14];
    const float* tb   = (const float*)d_in[15];
    const float* W1   = (const float*)d_in[16];
    const float* b1   = (const float*)d_in[17];
    const float* Ws   = (const float*)d_in[18];
    const float* bs   = (const float*)d_in[19];
    float* out = (float*)d_out;

    // ---- workspace layout (~55 MB) ----
    char* wsb = (char*)d_ws;
    size_t o = 0;
    auto alloc = [&](size_t bytes) -> void* {
        void* p = wsb + o;
        o = (o + bytes + 255) & ~(size_t)255;
        return p;
    };
    bf* f1b  = (bf*)alloc((size_t)NTOT * F3 * 2);     //  8 MB
    bf* f2b  = (bf*)alloc((size_t)NTOT * F3 * 2);     //  8 MB
    bf* X    = (bf*)alloc((size_t)NTOT * F1 * 2);     // 16 MB
    bf* Y    = (bf*)alloc((size_t)NTOT * F2 * 2);     // 12 MB
    int* off   = (int*)alloc((size_t)2 * (NTOT + 1) * 4);
    int* csrc  = (int*)alloc((size_t)2 * NEDGE * 4);  // 4 MB
    float* cnorm = (float*)alloc((size_t)2 * NEDGE * 4); // 4 MB
    int* deg   = (int*)alloc((size_t)2 * NTOT * 4);
    float* dinv = (float*)alloc((size_t)2 * NTOT * 4);
    int* cur   = (int*)alloc((size_t)2 * NTOT * 4);
    int* bsum  = (int*)alloc(2048);
    unsigned* smin = (unsigned*)alloc(BGR * 4);
    unsigned* smax = (unsigned*)alloc(BGR * 4);
    int* histc = (int*)alloc((size_t)BGR * BINS * 4);
    float* mean = (float*)alloc((size_t)2 * BGR * F3 * 4);
    float* ctx  = (float*)alloc((size_t)2 * BGR * F3 * 4);
    float* pools = (float*)alloc((size_t)2 * BGR * F3 * 4);
    float* coef = (float*)alloc((size_t)2 * NTOT * 4);
    (void)ws_size; (void)in_sizes; (void)n_in; (void)out_size;

    // inits (ws is re-poisoned before every call)
    fill_init_k<<<(BGR * BINS + 2 * BGR + 255) / 256, 256, 0, stream>>>(histc, smin, smax);
    fillz_k<<<(4 * NTOT) / 256, 256, 0, stream>>>((unsigned*)deg, 4 * NTOT);  // deg+cur contiguous? no: zero both
    fillz_k<<<(2 * NTOT) / 256, 256, 0, stream>>>((unsigned*)cur, 2 * NTOT);

    // ---- CSR build, both sides batched ----
    deg_k<<<dim3(NEDGE / 256, 2), 256, 0, stream>>>(ei1, ei2, deg);
    dinv_k<<<dim3(NTOT / 256, 2), 256, 0, stream>>>(deg, dinv);
    scan1_k<<<dim3(NTOT / 256, 2), 256, 0, stream>>>(deg, off, bsum);
    scan2_k<<<2, 256, 0, stream>>>(bsum);
    scan3_k<<<dim3(NTOT / 256, 2), 256, 0, stream>>>(off, bsum);
    scatter_k<<<dim3(NEDGE / 256, 2), 256, 0, stream>>>(ei1, ei2, off, cur, dinv, csrc, cnorm);

    // ---- GCN stack (sequential sides; X/Y shared) ----
    const float* xs[2] = {x1, x2};
    bf* fs[2] = {f1b, f2b};
    for (int s = 0; s < 2; s++) {
        const int* offs = off + s * (NTOT + 1);
        const int* cs   = csrc + (size_t)s * NEDGE;
        const float* cn = cnorm + (size_t)s * NEDGE;
        const float* dv = dinv + (size_t)s * NTOT;
        // z1 = A_hat x (fp32 in, NL wide) -> Y
        agg_k<NL, 0, 0, 1><<<(NTOT * (NL / 4)) / 256, 256, 0, stream>>>(xs[s], nullptr, offs, cs, cn, dv, Y);
        // h1 = relu(z1 Wc1 + bc1) -> X   [A_hat(xW) == (A_hat x)W]
        gemm_k<NL, F1, 1, 1><<<(NTOT * (F1 / 4)) / 256, 256, 0, stream>>>(Y, Wc1, bc1, X);
        // t2 = h1 Wc2 -> Y
        gemm_k<F1, F2, 0, 0><<<(NTOT * (F2 / 4)) / 256, 256, 0, stream>>>(X, Wc2, nullptr, Y);
        // h2 = relu(A_hat t2 + bc2) -> X
        agg_k<F2, 1, 1, 0><<<(NTOT * (F2 / 4)) / 256, 256, 0, stream>>>(Y, bc2, offs, cs, cn, dv, X);
        // t3 = h2 Wc3 -> Y
        gemm_k<F2, F3, 0, 0><<<(NTOT * (F3 / 4)) / 256, 256, 0, stream>>>(X, Wc3, nullptr, Y);
        // f = A_hat t3 + bc3 -> fs[s]
        agg_k<F3, 1, 0, 0><<<(NTOT * (F3 / 4)) / 256, 256, 0, stream>>>(Y, bc3, offs, cs, cn, dv, fs[s]);
    }

    // ---- MFMA histogram similarity: minmax pass then binning pass ----
    simm_k<<<BGR * 64, 256, 0, stream>>>(f1b, f2b, smin, smax);
    simh_k<<<BGR * 64, 256, 0, stream>>>(f1b, f2b, smin, smax, histc);

    // ---- attention pooling, both sides batched ----
    pool_k<<<dim3(BGR, 2), 256, 0, stream>>>(f1b, f2b, nullptr, mean, 1.0f / (float)NPG);
    ctx_k<<<dim3(BGR, 2), 64, 0, stream>>>(mean, Watt, ctx);
    coef_k<<<dim3((NTOT * 64) / 256, 2), 256, 0, stream>>>(f1b, f2b, ctx, coef);
    pool_k<<<dim3(BGR, 2), 256, 0, stream>>>(f1b, f2b, coef, pools, 1.0f);

    // ---- tensor network + MLP tail ----
    final_k<<<BGR, 256, 0, stream>>>(pools, Wt, Wtb, tb, histc, W1, b1, Ws, bs, out);
}

// Round 4
// 877.963 us; speedup vs baseline: 1.3506x; 1.2102x over previous
//
#include <hip/hip_runtime.h>
#include <math.h>

#define NTOT  65536
#define NEDGE 524288
#define BGR   128
#define NPG   512
#define NL    32
#define F1    128
#define F2    96
#define F3    64
#define KT    16
#define BINS  16
#define BN    32

typedef unsigned short bf;
typedef __attribute__((ext_vector_type(8))) short sv8;    // 8 bf16 fragment (4 VGPRs)
typedef __attribute__((ext_vector_type(16))) float fv16;  // 32x32 mfma accumulator

// ---------------- helpers ----------------
__device__ __forceinline__ float b2f(bf v) { return __uint_as_float(((unsigned)v) << 16); }
__device__ __forceinline__ bf f2b(float f) {
    unsigned u = __float_as_uint(f);
    return (bf)((u + 0x7FFF + ((u >> 16) & 1)) >> 16);  // RNE
}
__device__ __forceinline__ float sigm(float x) { return 1.f / (1.f + expf(-x)); }

// ---------------- init ----------------
__global__ __launch_bounds__(256) void fillz_k(unsigned* __restrict__ p, int n) {
    int i = blockIdx.x * 256 + threadIdx.x;
    if (i < n) p[i] = 0u;
}

// ---------------- CSR build (batched: blockIdx.y = side) ----------------
__global__ __launch_bounds__(256) void deg_k(const int* __restrict__ ei1, const int* __restrict__ ei2,
                                             int* __restrict__ deg) {
    int side = blockIdx.y;
    const int* dst = (side ? ei2 : ei1) + NEDGE;
    int e = blockIdx.x * 256 + threadIdx.x;
    atomicAdd(&deg[(size_t)side * NTOT + dst[e]], 1);
}

__global__ __launch_bounds__(256) void dinv_k(const int* __restrict__ deg, float* __restrict__ dinv) {
    int side = blockIdx.y;
    int n = side * NTOT + blockIdx.x * 256 + threadIdx.x;
    dinv[n] = 1.0f / sqrtf((float)deg[n] + 1.0f);
}

__global__ __launch_bounds__(256) void scan1_k(const int* __restrict__ deg, int* __restrict__ off, int* __restrict__ bsum) {
    __shared__ int s[256];
    int side = blockIdx.y;
    int t = threadIdx.x, b = blockIdx.x, i = b * 256 + t;
    int x = deg[side * NTOT + i];
    s[t] = x;
    __syncthreads();
    for (int o = 1; o < 256; o <<= 1) {
        int v = (t >= o) ? s[t - o] : 0;
        __syncthreads();
        s[t] += v;
        __syncthreads();
    }
    off[side * (NTOT + 1) + i] = s[t] - x;
    if (t == 255) bsum[side * 256 + b] = s[255];
}

__global__ __launch_bounds__(256) void scan2_k(int* __restrict__ bsum) {
    __shared__ int s[256];
    int side = blockIdx.x;
    int t = threadIdx.x;
    int x = bsum[side * 256 + t];
    s[t] = x;
    __syncthreads();
    for (int o = 1; o < 256; o <<= 1) {
        int v = (t >= o) ? s[t - o] : 0;
        __syncthreads();
        s[t] += v;
        __syncthreads();
    }
    bsum[side * 256 + t] = s[t] - x;  // exclusive
}

__global__ __launch_bounds__(256) void scan3_k(int* __restrict__ off, const int* __restrict__ bsum) {
    int side = blockIdx.y;
    int i = blockIdx.x * 256 + threadIdx.x;
    off[side * (NTOT + 1) + i] += bsum[side * 256 + (i >> 8)];
    if (i == 0) off[side * (NTOT + 1) + NTOT] = NEDGE;
}

__global__ __launch_bounds__(256) void scatter_k(const int* __restrict__ ei1, const int* __restrict__ ei2,
                                                 const int* __restrict__ off, int* __restrict__ cur,
                                                 const float* __restrict__ dinv,
                                                 int* __restrict__ csrc, float* __restrict__ cnorm) {
    int side = blockIdx.y;
    const int* src = side ? ei2 : ei1;
    const int* dst = src + NEDGE;
    int e = blockIdx.x * 256 + threadIdx.x;
    int s = src[e], d = dst[e];
    int p = atomicAdd(&cur[(size_t)side * NTOT + d], 1);
    int idx = off[side * (NTOT + 1) + d] + p;
    csrc[(size_t)side * NEDGE + idx] = s;
    cnorm[(size_t)side * NEDGE + idx] = dinv[side * NTOT + s] * dinv[side * NTOT + d];
}

// ---------------- GEMM: out[NT x COUT](bf16) = X[NT x CIN](bf16) @ W(fp32) ----------------
template <int CIN, int COUT, int BIAS, int RELU>
__global__ __launch_bounds__(256) void gemm_k(const bf* __restrict__ X, const float* __restrict__ Wm,
                                              const float* __restrict__ bias, bf* __restrict__ out) {
    constexpr int C4 = COUT / 4;
    int t = blockIdx.x * 256 + threadIdx.x;
    int row = t / C4;
    int c = (t % C4) * 4;
    const bf* xr = X + (size_t)row * CIN;
    float ax = 0.f, ay = 0.f, az = 0.f, aw = 0.f;
#pragma unroll 2
    for (int k = 0; k < CIN; k += 4) {
        ushort4 xv = *(const ushort4*)(xr + k);
        float a0 = b2f(xv.x), a1 = b2f(xv.y), a2 = b2f(xv.z), a3 = b2f(xv.w);
        float4 w0 = *(const float4*)(Wm + (size_t)(k + 0) * COUT + c);
        float4 w1 = *(const float4*)(Wm + (size_t)(k + 1) * COUT + c);
        float4 w2 = *(const float4*)(Wm + (size_t)(k + 2) * COUT + c);
        float4 w3 = *(const float4*)(Wm + (size_t)(k + 3) * COUT + c);
        ax += a0 * w0.x + a1 * w1.x + a2 * w2.x + a3 * w3.x;
        ay += a0 * w0.y + a1 * w1.y + a2 * w2.y + a3 * w3.y;
        az += a0 * w0.z + a1 * w1.z + a2 * w2.z + a3 * w3.z;
        aw += a0 * w0.w + a1 * w1.w + a2 * w2.w + a3 * w3.w;
    }
    if (BIAS) {
        float4 bv = *(const float4*)(bias + c);
        ax += bv.x; ay += bv.y; az += bv.z; aw += bv.w;
    }
    if (RELU) {
        ax = fmaxf(ax, 0.f); ay = fmaxf(ay, 0.f); az = fmaxf(az, 0.f); aw = fmaxf(aw, 0.f);
    }
    ushort4 o;
    o.x = f2b(ax); o.y = f2b(ay); o.z = f2b(az); o.w = f2b(aw);
    *(ushort4*)(out + (size_t)row * COUT + c) = o;
}

// ---------------- GCN aggregation (gather via CSR), bf16 or fp32 input -> bf16 out -------
template <int C, int BIAS, int RELU, int FIN32>
__global__ __launch_bounds__(256) void agg_k(const void* __restrict__ hin_, const float* __restrict__ bias,
                                             const int* __restrict__ off, const int* __restrict__ esrc,
                                             const float* __restrict__ enorm, const float* __restrict__ dinv,
                                             bf* __restrict__ out) {
    constexpr int C4 = C / 4;
    int t = blockIdx.x * 256 + threadIdx.x;
    int node = t / C4;
    int c = (t % C4) * 4;
    float d = dinv[node];
    float sc = d * d;
    float ax, ay, az, aw;
    if (FIN32) {
        const float* hin = (const float*)hin_;
        float4 h = *(const float4*)(hin + (size_t)node * C + c);
        ax = h.x * sc; ay = h.y * sc; az = h.z * sc; aw = h.w * sc;
    } else {
        const bf* hin = (const bf*)hin_;
        ushort4 h = *(const ushort4*)(hin + (size_t)node * C + c);
        ax = b2f(h.x) * sc; ay = b2f(h.y) * sc; az = b2f(h.z) * sc; aw = b2f(h.w) * sc;
    }
    int e0 = off[node], e1 = off[node + 1];
    for (int j = e0; j < e1; j++) {
        int s = esrc[j];
        float w = enorm[j];
        if (FIN32) {
            const float* hin = (const float*)hin_;
            float4 hs = *(const float4*)(hin + (size_t)s * C + c);
            ax += w * hs.x; ay += w * hs.y; az += w * hs.z; aw += w * hs.w;
        } else {
            const bf* hin = (const bf*)hin_;
            ushort4 hs = *(const ushort4*)(hin + (size_t)s * C + c);
            ax += w * b2f(hs.x); ay += w * b2f(hs.y); az += w * b2f(hs.z); aw += w * b2f(hs.w);
        }
    }
    if (BIAS) {
        float4 bv = *(const float4*)(bias + c);
        ax += bv.x; ay += bv.y; az += bv.z; aw += bv.w;
    }
    if (RELU) {
        ax = fmaxf(ax, 0.f); ay = fmaxf(ay, 0.f); az = fmaxf(az, 0.f); aw = fmaxf(aw, 0.f);
    }
    ushort4 o;
    o.x = f2b(ax); o.y = f2b(ay); o.z = f2b(az); o.w = f2b(aw);
    *(ushort4*)(out + (size_t)node * C + c) = o;
}

// ---------------- MFMA similarity ----------------
// grid = dim3(16, BGR): blockIdx.y = graph, blockIdx.x = mt (32-row stripe).
// Block = 4 waves; wave handles nt = 4j+wave, j=0..3 (16 column tiles per block).
// Fragments are 8 contiguous bf16 per lane -> direct 16B global loads, no LDS.
// Each block OWNS its output slot -> no global atomics anywhere.
__global__ __launch_bounds__(256) void simm_k(const bf* __restrict__ f1, const bf* __restrict__ f2,
                                              float* __restrict__ statmin, float* __restrict__ statmax) {
    int g = blockIdx.y, mt = blockIdx.x;
    int t = threadIdx.x, wave = t >> 6, lane = t & 63;
    int half = lane >> 5, r = lane & 31;
    const bf* Ap = f1 + ((size_t)g * NPG + mt * 32 + r) * F3 + half * 8;
    sv8 a0 = *(const sv8*)(Ap +  0);
    sv8 a1 = *(const sv8*)(Ap + 16);
    sv8 a2 = *(const sv8*)(Ap + 32);
    sv8 a3 = *(const sv8*)(Ap + 48);
    float mn = 1e30f, mx = -1e30f;
#pragma unroll
    for (int j = 0; j < 4; j++) {
        int nt = j * 4 + wave;
        const bf* Bp = f2 + ((size_t)g * NPG + nt * 32 + r) * F3 + half * 8;
        fv16 acc;
#pragma unroll
        for (int i = 0; i < 16; i++) acc[i] = 0.f;
        acc = __builtin_amdgcn_mfma_f32_32x32x16_bf16(a0, *(const sv8*)(Bp +  0), acc, 0, 0, 0);
        acc = __builtin_amdgcn_mfma_f32_32x32x16_bf16(a1, *(const sv8*)(Bp + 16), acc, 0, 0, 0);
        acc = __builtin_amdgcn_mfma_f32_32x32x16_bf16(a2, *(const sv8*)(Bp + 32), acc, 0, 0, 0);
        acc = __builtin_amdgcn_mfma_f32_32x32x16_bf16(a3, *(const sv8*)(Bp + 48), acc, 0, 0, 0);
#pragma unroll
        for (int i = 0; i < 16; i++) {
            mn = fminf(mn, acc[i]);
            mx = fmaxf(mx, acc[i]);
        }
    }
    for (int o = 32; o; o >>= 1) {
        mn = fminf(mn, __shfl_down(mn, o));
        mx = fmaxf(mx, __shfl_down(mx, o));
    }
    __shared__ float smn[4], smx[4];
    if (lane == 0) { smn[wave] = mn; smx[wave] = mx; }
    __syncthreads();
    if (t == 0) {
        statmin[g * 16 + mt] = fminf(fminf(smn[0], smn[1]), fminf(smn[2], smn[3]));
        statmax[g * 16 + mt] = fmaxf(fmaxf(smx[0], smx[1]), fmaxf(smx[2], smx[3]));
    }
}

__global__ __launch_bounds__(256) void simh_k(const bf* __restrict__ f1, const bf* __restrict__ f2,
                                              const float* __restrict__ statmin, const float* __restrict__ statmax,
                                              int* __restrict__ hist_p) {
    __shared__ int ph[256 * 17];   // per-THREAD private hist, stride 17 (bank-spread)
    __shared__ int pr[256];
    int g = blockIdx.y, mt = blockIdx.x;
    int t = threadIdx.x, wave = t >> 6, lane = t & 63;
#pragma unroll
    for (int b = 0; b < BINS; b++) ph[t * 17 + b] = 0;

    // global min/max from the 16 per-stripe partials (redundant per wave, cheap)
    float pm = (lane < 16) ? statmin[g * 16 + lane] : 1e30f;
    float px = (lane < 16) ? statmax[g * 16 + lane] : -1e30f;
    for (int o = 8; o; o >>= 1) {
        pm = fminf(pm, __shfl_down(pm, o));
        px = fmaxf(px, __shfl_down(px, o));
    }
    float vmin = sigm(__shfl(pm, 0));
    float vmax = sigm(__shfl(px, 0));
    float width = (vmax - vmin) / (float)BINS;
    float inv = 1.0f / (width > 0.f ? width : 1.0f);

    int half = lane >> 5, r = lane & 31;
    const bf* Ap = f1 + ((size_t)g * NPG + mt * 32 + r) * F3 + half * 8;
    sv8 a0 = *(const sv8*)(Ap +  0);
    sv8 a1 = *(const sv8*)(Ap + 16);
    sv8 a2 = *(const sv8*)(Ap + 32);
    sv8 a3 = *(const sv8*)(Ap + 48);
#pragma unroll
    for (int j = 0; j < 4; j++) {
        int nt = j * 4 + wave;
        const bf* Bp = f2 + ((size_t)g * NPG + nt * 32 + r) * F3 + half * 8;
        fv16 acc;
#pragma unroll
        for (int i = 0; i < 16; i++) acc[i] = 0.f;
        acc = __builtin_amdgcn_mfma_f32_32x32x16_bf16(a0, *(const sv8*)(Bp +  0), acc, 0, 0, 0);
        acc = __builtin_amdgcn_mfma_f32_32x32x16_bf16(a1, *(const sv8*)(Bp + 16), acc, 0, 0, 0);
        acc = __builtin_amdgcn_mfma_f32_32x32x16_bf16(a2, *(const sv8*)(Bp + 32), acc, 0, 0, 0);
        acc = __builtin_amdgcn_mfma_f32_32x32x16_bf16(a3, *(const sv8*)(Bp + 48), acc, 0, 0, 0);
#pragma unroll
        for (int i = 0; i < 16; i++) {
            float v = sigm(acc[i]);
            int bi = (int)floorf((v - vmin) * inv);
            bi = bi < 0 ? 0 : (bi > BINS - 1 ? BINS - 1 : bi);
            ph[t * 17 + bi] += 1;   // private -> plain RMW, no atomic
        }
    }
    __syncthreads();
    // stage 1: thread t sums 16 thread-hists: group=t>>4 over rows group*16..+15, bin=t&15
    {
        int grp = t >> 4, bin = t & 15;
        int s = 0;
#pragma unroll
        for (int j = 0; j < 16; j++) s += ph[(grp * 16 + j) * 17 + bin];
        pr[t] = s;
    }
    __syncthreads();
    if (t < BINS) {
        int tot = 0;
#pragma unroll
        for (int j = 0; j < 16; j++) tot += pr[j * 16 + t];
        hist_p[((size_t)g * 16 + mt) * BINS + t] = tot;   // block-owned slot
    }
}

// ---------------- attention pool (batched over sides via blockIdx.y) ----------------
__global__ __launch_bounds__(256) void pool_k(const bf* __restrict__ f1, const bf* __restrict__ f2,
                                              const float* __restrict__ wbase,
                                              float* __restrict__ outbase, float scale) {
    int side = blockIdx.y;
    const bf* x = side ? f2 : f1;
    const float* w = wbase ? wbase + (size_t)side * NTOT : nullptr;
    float* out = outbase + (size_t)side * BGR * F3;
    int b = blockIdx.x, t = threadIdx.x;
    int f = t & 63, gq = t >> 6;
    float acc = 0.f;
    for (int r = gq; r < NPG; r += 4) {
        int n = b * NPG + r;
        float c = w ? w[n] : 1.0f;
        acc += c * b2f(x[(size_t)n * F3 + f]);
    }
    __shared__ float red[256];
    red[t] = acc;
    __syncthreads();
    if (gq == 0) {
        float s = red[f] + red[64 + f] + red[128 + f] + red[192 + f];
        out[b * F3 + f] = s * scale;
    }
}

__global__ void ctx_k(const float* __restrict__ meanb, const float* __restrict__ Watt, float* __restrict__ ctxb) {
    int side = blockIdx.y;
    const float* mean = meanb + (size_t)side * BGR * F3;
    float* ctx = ctxb + (size_t)side * BGR * F3;
    int b = blockIdx.x, j = threadIdx.x;  // 64 threads
    float acc = 0.f;
#pragma unroll 8
    for (int i = 0; i < F3; i++) acc += mean[b * F3 + i] * Watt[i * F3 + j];
    ctx[b * F3 + j] = tanhf(acc);
}

__global__ __launch_bounds__(256) void coef_k(const bf* __restrict__ f1, const bf* __restrict__ f2,
                                              const float* __restrict__ ctxb, float* __restrict__ coefb) {
    int side = blockIdx.y;
    const bf* x = side ? f2 : f1;
    const float* ctx = ctxb + (size_t)side * BGR * F3;
    float* coef = coefb + (size_t)side * NTOT;
    int t = blockIdx.x * 256 + threadIdx.x;
    int n = t >> 6;
    int f = t & 63;
    int b = n >> 9;  // N = 512
    float v = b2f(x[(size_t)n * F3 + f]) * ctx[b * F3 + f];
    for (int o = 32; o; o >>= 1) v += __shfl_down(v, o);
    if (f == 0) coef[n] = sigm(v);
}

// ---------------- tensor network + tail MLP ----------------
__global__ __launch_bounds__(256) void final_k(const float* __restrict__ pools,
                                               const float* __restrict__ Wt, const float* __restrict__ Wtb,
                                               const float* __restrict__ tb, const int* __restrict__ hist_p,
                                               const float* __restrict__ W1, const float* __restrict__ b1,
                                               const float* __restrict__ Ws, const float* __restrict__ bs,
                                               float* __restrict__ out) {
    const float* p1 = pools;
    const float* p2 = pools + (size_t)BGR * F3;
    int b = blockIdx.x, t = threadIdx.x;
    __shared__ float cat[128];
    __shared__ float sacc[256];
    __shared__ float feat[32];
    __shared__ float hb[32];
    if (t < 64) cat[t] = p1[b * F3 + t];
    else if (t < 128) cat[t] = p2[b * F3 + (t - 64)];
    __syncthreads();
    int k = t & 15, c = t >> 4;
    float acc = 0.f;
    for (int q = 0; q < 256; q++) {
        int ij = c * 256 + q;
        int i = ij >> 6, j = ij & 63;
        acc += cat[i] * cat[64 + j] * Wt[ij * KT + k];
    }
    sacc[t] = acc;
    __syncthreads();
    if (t < KT) {
        float sc = 0.f;
        for (int c2 = 0; c2 < 16; c2++) sc += sacc[c2 * 16 + t];
        float bt = 0.f;
        for (int i = 0; i < 128; i++) bt += cat[i] * Wtb[t * 128 + i];
        float tv = sc + bt + tb[t];
        feat[t] = tv > 0.f ? tv : 0.f;
        int hsum = 0;
#pragma unroll
        for (int j = 0; j < 16; j++) hsum += hist_p[((size_t)b * 16 + j) * BINS + t];
        feat[KT + t] = (float)hsum * (1.0f / (float)(NPG * NPG));
    }
    __syncthreads();
    if (t < BN) {
        float a = 0.f;
        for (int i = 0; i < KT + BINS; i++) a += feat[i] * W1[i * BN + t];
        a += b1[t];
        hb[t] = a > 0.f ? a : 0.f;
    }
    __syncthreads();
    if (t == 0) {
        float s = bs[0];
        for (int j = 0; j < BN; j++) s += hb[j] * Ws[j];
        out[b] = sigm(s);
    }
}

// ---------------- launch ----------------
extern "C" void kernel_launch(void* const* d_in, const int* in_sizes, int n_in,
                              void* d_out, int out_size, void* d_ws, size_t ws_size,
                              hipStream_t stream) {
    const float* x1   = (const float*)d_in[0];
    const float* x2   = (const float*)d_in[1];
    const int*   ei1  = (const int*)d_in[2];
    const int*   ei2  = (const int*)d_in[3];
    const float* Wc1  = (const float*)d_in[6];
    const float* bc1  = (const float*)d_in[7];
    const float* Wc2  = (const float*)d_in[8];
    const float* bc2  = (const float*)d_in[9];
    const float* Wc3  = (const float*)d_in[10];
    const float* bc3  = (const float*)d_in[11];
    const float* Watt = (const float*)d_in[12];
    const float* Wt   = (const float*)d_in[13];
    const float* Wtb  = (const float*)d_in[14];
    const float* tb   = (const float*)d_in[15];
    const float* W1   = (const float*)d_in[16];
    const float* b1   = (const float*)d_in[17];
    const float* Ws   = (const float*)d_in[18];
    const float* bs   = (const float*)d_in[19];
    float* out = (float*)d_out;

    // ---- workspace layout (~55 MB) ----
    char* wsb = (char*)d_ws;
    size_t o = 0;
    auto alloc = [&](size_t bytes) -> void* {
        void* p = wsb + o;
        o = (o + bytes + 255) & ~(size_t)255;
        return p;
    };
    bf* f1b  = (bf*)alloc((size_t)NTOT * F3 * 2);     //  8 MB
    bf* f2b  = (bf*)alloc((size_t)NTOT * F3 * 2);     //  8 MB
    bf* X    = (bf*)alloc((size_t)NTOT * F1 * 2);     // 16 MB
    bf* Y    = (bf*)alloc((size_t)NTOT * F2 * 2);     // 12 MB
    int* off   = (int*)alloc((size_t)2 * (NTOT + 1) * 4);
    int* csrc  = (int*)alloc((size_t)2 * NEDGE * 4);  // 4 MB
    float* cnorm = (float*)alloc((size_t)2 * NEDGE * 4); // 4 MB
    int* deg   = (int*)alloc((size_t)2 * NTOT * 4);
    float* dinv = (float*)alloc((size_t)2 * NTOT * 4);
    int* cur   = (int*)alloc((size_t)2 * NTOT * 4);
    int* bsum  = (int*)alloc(2048);
    float* statmin = (float*)alloc((size_t)BGR * 16 * 4);
    float* statmax = (float*)alloc((size_t)BGR * 16 * 4);
    int* hist_p = (int*)alloc((size_t)BGR * 16 * BINS * 4);  // 128 KB, block-owned
    float* mean = (float*)alloc((size_t)2 * BGR * F3 * 4);
    float* ctx  = (float*)alloc((size_t)2 * BGR * F3 * 4);
    float* pools = (float*)alloc((size_t)2 * BGR * F3 * 4);
    float* coef = (float*)alloc((size_t)2 * NTOT * 4);
    (void)ws_size; (void)in_sizes; (void)n_in; (void)out_size;

    // inits (ws is re-poisoned before every call); stat/hist need none (owner-written)
    fillz_k<<<(2 * NTOT) / 256, 256, 0, stream>>>((unsigned*)deg, 2 * NTOT);
    fillz_k<<<(2 * NTOT) / 256, 256, 0, stream>>>((unsigned*)cur, 2 * NTOT);

    // ---- CSR build, both sides batched ----
    deg_k<<<dim3(NEDGE / 256, 2), 256, 0, stream>>>(ei1, ei2, deg);
    dinv_k<<<dim3(NTOT / 256, 2), 256, 0, stream>>>(deg, dinv);
    scan1_k<<<dim3(NTOT / 256, 2), 256, 0, stream>>>(deg, off, bsum);
    scan2_k<<<2, 256, 0, stream>>>(bsum);
    scan3_k<<<dim3(NTOT / 256, 2), 256, 0, stream>>>(off, bsum);
    scatter_k<<<dim3(NEDGE / 256, 2), 256, 0, stream>>>(ei1, ei2, off, cur, dinv, csrc, cnorm);

    // ---- GCN stack (sequential sides; X/Y shared) ----
    const float* xs[2] = {x1, x2};
    bf* fs[2] = {f1b, f2b};
    for (int s = 0; s < 2; s++) {
        const int* offs = off + s * (NTOT + 1);
        const int* cs   = csrc + (size_t)s * NEDGE;
        const float* cn = cnorm + (size_t)s * NEDGE;
        const float* dv = dinv + (size_t)s * NTOT;
        // z1 = A_hat x (fp32 in, NL wide) -> Y
        agg_k<NL, 0, 0, 1><<<(NTOT * (NL / 4)) / 256, 256, 0, stream>>>(xs[s], nullptr, offs, cs, cn, dv, Y);
        // h1 = relu(z1 Wc1 + bc1) -> X   [A_hat(xW) == (A_hat x)W]
        gemm_k<NL, F1, 1, 1><<<(NTOT * (F1 / 4)) / 256, 256, 0, stream>>>(Y, Wc1, bc1, X);
        // t2 = h1 Wc2 -> Y
        gemm_k<F1, F2, 0, 0><<<(NTOT * (F2 / 4)) / 256, 256, 0, stream>>>(X, Wc2, nullptr, Y);
        // h2 = relu(A_hat t2 + bc2) -> X
        agg_k<F2, 1, 1, 0><<<(NTOT * (F2 / 4)) / 256, 256, 0, stream>>>(Y, bc2, offs, cs, cn, dv, X);
        // t3 = h2 Wc3 -> Y
        gemm_k<F2, F3, 0, 0><<<(NTOT * (F3 / 4)) / 256, 256, 0, stream>>>(X, Wc3, nullptr, Y);
        // f = A_hat t3 + bc3 -> fs[s]
        agg_k<F3, 1, 0, 0><<<(NTOT * (F3 / 4)) / 256, 256, 0, stream>>>(Y, bc3, offs, cs, cn, dv, fs[s]);
    }

    // ---- MFMA histogram similarity: per-stripe minmax partials, then binning ----
    simm_k<<<dim3(16, BGR), 256, 0, stream>>>(f1b, f2b, statmin, statmax);
    simh_k<<<dim3(16, BGR), 256, 0, stream>>>(f1b, f2b, statmin, statmax, hist_p);

    // ---- attention pooling, both sides batched ----
    pool_k<<<dim3(BGR, 2), 256, 0, stream>>>(f1b, f2b, nullptr, mean, 1.0f / (float)NPG);
    ctx_k<<<dim3(BGR, 2), 64, 0, stream>>>(mean, Watt, ctx);
    coef_k<<<dim3((NTOT * 64) / 256, 2), 256, 0, stream>>>(f1b, f2b, ctx, coef);
    pool_k<<<dim3(BGR, 2), 256, 0, stream>>>(f1b, f2b, coef, pools, 1.0f);

    // ---- tensor network + MLP tail ----
    final_k<<<BGR, 256, 0, stream>>>(pools, Wt, Wtb, tb, hist_p, W1, b1, Ws, bs, out);
}

// Round 5
// 565.497 us; speedup vs baseline: 2.0968x; 1.5526x over previous
//
#include <hip/hip_runtime.h>
#include <math.h>

#define NTOT  65536
#define NEDGE 524288
#define BGR   128
#define NPG   512
#define NL    32
#define F1    128
#define F2    96
#define F3    64
#define KT    16
#define BINS  16
#define BN    32

typedef unsigned short bf;
typedef __attribute__((ext_vector_type(8))) short sv8;    // 8 bf16 fragment (4 VGPRs)
typedef __attribute__((ext_vector_type(16))) float fv16;  // 32x32 mfma accumulator

// ---------------- helpers ----------------
__device__ __forceinline__ float b2f(bf v) { return __uint_as_float(((unsigned)v) << 16); }
__device__ __forceinline__ bf f2b(float f) {
    unsigned u = __float_as_uint(f);
    return (bf)((u + 0x7FFF + ((u >> 16) & 1)) >> 16);  // RNE
}
__device__ __forceinline__ float sigm(float x) { return 1.f / (1.f + expf(-x)); }

// ---------------- init ----------------
__global__ __launch_bounds__(256) void fillz_k(unsigned* __restrict__ p, int n) {
    int i = blockIdx.x * 256 + threadIdx.x;
    if (i < n) p[i] = 0u;
}

// transpose+convert weight: Wt[cout][cin] (bf16) from W[cin][cout] (fp32)
__global__ __launch_bounds__(256) void wconv_k(const float* __restrict__ W, bf* __restrict__ Wt,
                                               int cin, int cout) {
    int i = blockIdx.x * 256 + threadIdx.x;
    if (i < cin * cout) {
        int co = i / cin, ci = i - co * cin;
        Wt[co * cin + ci] = f2b(W[ci * cout + co]);
    }
}

// ---------------- CSR build (batched: blockIdx.y = side) ----------------
__global__ __launch_bounds__(256) void deg_k(const int* __restrict__ ei1, const int* __restrict__ ei2,
                                             int* __restrict__ deg) {
    int side = blockIdx.y;
    const int* dst = (side ? ei2 : ei1) + NEDGE;
    int e = blockIdx.x * 256 + threadIdx.x;
    atomicAdd(&deg[(size_t)side * NTOT + dst[e]], 1);
}

__global__ __launch_bounds__(256) void dinv_k(const int* __restrict__ deg, float* __restrict__ dinv) {
    int side = blockIdx.y;
    int n = side * NTOT + blockIdx.x * 256 + threadIdx.x;
    dinv[n] = 1.0f / sqrtf((float)deg[n] + 1.0f);
}

__global__ __launch_bounds__(256) void scan1_k(const int* __restrict__ deg, int* __restrict__ off, int* __restrict__ bsum) {
    __shared__ int s[256];
    int side = blockIdx.y;
    int t = threadIdx.x, b = blockIdx.x, i = b * 256 + t;
    int x = deg[side * NTOT + i];
    s[t] = x;
    __syncthreads();
    for (int o = 1; o < 256; o <<= 1) {
        int v = (t >= o) ? s[t - o] : 0;
        __syncthreads();
        s[t] += v;
        __syncthreads();
    }
    off[side * (NTOT + 1) + i] = s[t] - x;
    if (t == 255) bsum[side * 256 + b] = s[255];
}

__global__ __launch_bounds__(256) void scan2_k(int* __restrict__ bsum) {
    __shared__ int s[256];
    int side = blockIdx.x;
    int t = threadIdx.x;
    int x = bsum[side * 256 + t];
    s[t] = x;
    __syncthreads();
    for (int o = 1; o < 256; o <<= 1) {
        int v = (t >= o) ? s[t - o] : 0;
        __syncthreads();
        s[t] += v;
        __syncthreads();
    }
    bsum[side * 256 + t] = s[t] - x;  // exclusive
}

__global__ __launch_bounds__(256) void scan3_k(int* __restrict__ off, const int* __restrict__ bsum) {
    int side = blockIdx.y;
    int i = blockIdx.x * 256 + threadIdx.x;
    off[side * (NTOT + 1) + i] += bsum[side * 256 + (i >> 8)];
    if (i == 0) off[side * (NTOT + 1) + NTOT] = NEDGE;
}

__global__ __launch_bounds__(256) void scatter_k(const int* __restrict__ ei1, const int* __restrict__ ei2,
                                                 const int* __restrict__ off, int* __restrict__ cur,
                                                 const float* __restrict__ dinv,
                                                 int* __restrict__ csrc, float* __restrict__ cnorm) {
    int side = blockIdx.y;
    const int* src = side ? ei2 : ei1;
    const int* dst = src + NEDGE;
    int e = blockIdx.x * 256 + threadIdx.x;
    int s = src[e], d = dst[e];
    int p = atomicAdd(&cur[(size_t)side * NTOT + d], 1);
    int idx = off[side * (NTOT + 1) + d] + p;
    csrc[(size_t)side * NEDGE + idx] = s;
    cnorm[(size_t)side * NEDGE + idx] = dinv[side * NTOT + s] * dinv[side * NTOT + d];
}

// ---------------- MFMA GEMM: out[NT x COUT](bf16) = X[NT x CIN](bf16) @ W ----------------
// Wt is [COUT x CIN] bf16 (transposed weight). One wave = 32-row stripe, loops
// over COUT/32 column tiles; A fragments (CIN/16 x sv8) loaded once, direct
// global 16B loads; Wt rows are L1-hot. C/D map: col=lane&31 (n), row=(reg&3)+
// 8*(reg>>2)+4*(lane>>5) (m).
template <int CIN, int COUT, int BIAS, int RELU>
__global__ __launch_bounds__(256) void gemmm_k(const bf* __restrict__ X, const bf* __restrict__ Wt,
                                               const float* __restrict__ bias, bf* __restrict__ out) {
    int wave = threadIdx.x >> 6, lane = threadIdx.x & 63;
    int half = lane >> 5, r = lane & 31;
    int row0 = blockIdx.x * 128 + wave * 32;
    const bf* Ap = X + (size_t)(row0 + r) * CIN + half * 8;
    sv8 a[CIN / 16];
#pragma unroll
    for (int k = 0; k < CIN / 16; k++) a[k] = *(const sv8*)(Ap + k * 16);
#pragma unroll
    for (int nt = 0; nt < COUT / 32; nt++) {
        const bf* Bp = Wt + (size_t)(nt * 32 + r) * CIN + half * 8;
        fv16 acc;
#pragma unroll
        for (int i = 0; i < 16; i++) acc[i] = 0.f;
#pragma unroll
        for (int k = 0; k < CIN / 16; k++)
            acc = __builtin_amdgcn_mfma_f32_32x32x16_bf16(a[k], *(const sv8*)(Bp + k * 16), acc, 0, 0, 0);
        float bv = BIAS ? bias[nt * 32 + r] : 0.f;
#pragma unroll
        for (int i = 0; i < 16; i++) {
            int rr = (i & 3) + 8 * (i >> 2) + 4 * half;
            float v = acc[i] + bv;
            if (RELU) v = fmaxf(v, 0.f);
            out[(size_t)(row0 + rr) * COUT + nt * 32 + r] = f2b(v);
        }
    }
}

// ---------------- GCN aggregation (gather via CSR), bf16 or fp32 input -> bf16 out -------
template <int C, int BIAS, int RELU, int FIN32>
__global__ __launch_bounds__(256) void agg_k(const void* __restrict__ hin_, const float* __restrict__ bias,
                                             const int* __restrict__ off, const int* __restrict__ esrc,
                                             const float* __restrict__ enorm, const float* __restrict__ dinv,
                                             bf* __restrict__ out) {
    constexpr int C4 = C / 4;
    int t = blockIdx.x * 256 + threadIdx.x;
    int node = t / C4;
    int c = (t % C4) * 4;
    float d = dinv[node];
    float sc = d * d;
    float ax, ay, az, aw;
    if (FIN32) {
        const float* hin = (const float*)hin_;
        float4 h = *(const float4*)(hin + (size_t)node * C + c);
        ax = h.x * sc; ay = h.y * sc; az = h.z * sc; aw = h.w * sc;
    } else {
        const bf* hin = (const bf*)hin_;
        ushort4 h = *(const ushort4*)(hin + (size_t)node * C + c);
        ax = b2f(h.x) * sc; ay = b2f(h.y) * sc; az = b2f(h.z) * sc; aw = b2f(h.w) * sc;
    }
    int e0 = off[node], e1 = off[node + 1];
    for (int j = e0; j < e1; j++) {
        int s = esrc[j];
        float w = enorm[j];
        if (FIN32) {
            const float* hin = (const float*)hin_;
            float4 hs = *(const float4*)(hin + (size_t)s * C + c);
            ax += w * hs.x; ay += w * hs.y; az += w * hs.z; aw += w * hs.w;
        } else {
            const bf* hin = (const bf*)hin_;
            ushort4 hs = *(const ushort4*)(hin + (size_t)s * C + c);
            ax += w * b2f(hs.x); ay += w * b2f(hs.y); az += w * b2f(hs.z); aw += w * b2f(hs.w);
        }
    }
    if (BIAS) {
        float4 bv = *(const float4*)(bias + c);
        ax += bv.x; ay += bv.y; az += bv.z; aw += bv.w;
    }
    if (RELU) {
        ax = fmaxf(ax, 0.f); ay = fmaxf(ay, 0.f); az = fmaxf(az, 0.f); aw = fmaxf(aw, 0.f);
    }
    ushort4 o;
    o.x = f2b(ax); o.y = f2b(ay); o.z = f2b(az); o.w = f2b(aw);
    *(ushort4*)(out + (size_t)node * C + c) = o;
}

// ---------------- MFMA similarity ----------------
__global__ __launch_bounds__(256) void simm_k(const bf* __restrict__ f1, const bf* __restrict__ f2,
                                              float* __restrict__ statmin, float* __restrict__ statmax) {
    int g = blockIdx.y, mt = blockIdx.x;
    int t = threadIdx.x, wave = t >> 6, lane = t & 63;
    int half = lane >> 5, r = lane & 31;
    const bf* Ap = f1 + ((size_t)g * NPG + mt * 32 + r) * F3 + half * 8;
    sv8 a0 = *(const sv8*)(Ap +  0);
    sv8 a1 = *(const sv8*)(Ap + 16);
    sv8 a2 = *(const sv8*)(Ap + 32);
    sv8 a3 = *(const sv8*)(Ap + 48);
    float mn = 1e30f, mx = -1e30f;
#pragma unroll
    for (int j = 0; j < 4; j++) {
        int nt = j * 4 + wave;
        const bf* Bp = f2 + ((size_t)g * NPG + nt * 32 + r) * F3 + half * 8;
        fv16 acc;
#pragma unroll
        for (int i = 0; i < 16; i++) acc[i] = 0.f;
        acc = __builtin_amdgcn_mfma_f32_32x32x16_bf16(a0, *(const sv8*)(Bp +  0), acc, 0, 0, 0);
        acc = __builtin_amdgcn_mfma_f32_32x32x16_bf16(a1, *(const sv8*)(Bp + 16), acc, 0, 0, 0);
        acc = __builtin_amdgcn_mfma_f32_32x32x16_bf16(a2, *(const sv8*)(Bp + 32), acc, 0, 0, 0);
        acc = __builtin_amdgcn_mfma_f32_32x32x16_bf16(a3, *(const sv8*)(Bp + 48), acc, 0, 0, 0);
#pragma unroll
        for (int i = 0; i < 16; i++) {
            mn = fminf(mn, acc[i]);
            mx = fmaxf(mx, acc[i]);
        }
    }
    for (int o = 32; o; o >>= 1) {
        mn = fminf(mn, __shfl_down(mn, o));
        mx = fmaxf(mx, __shfl_down(mx, o));
    }
    __shared__ float smn[4], smx[4];
    if (lane == 0) { smn[wave] = mn; smx[wave] = mx; }
    __syncthreads();
    if (t == 0) {
        statmin[g * 16 + mt] = fminf(fminf(smn[0], smn[1]), fminf(smn[2], smn[3]));
        statmax[g * 16 + mt] = fmaxf(fmaxf(smx[0], smx[1]), fmaxf(smx[2], smx[3]));
    }
}

__global__ __launch_bounds__(256) void simh_k(const bf* __restrict__ f1, const bf* __restrict__ f2,
                                              const float* __restrict__ statmin, const float* __restrict__ statmax,
                                              int* __restrict__ hist_p) {
    __shared__ int ph[256 * 17];   // per-THREAD private hist, stride 17 (bank-spread)
    __shared__ int pr[256];
    int g = blockIdx.y, mt = blockIdx.x;
    int t = threadIdx.x, wave = t >> 6, lane = t & 63;
#pragma unroll
    for (int b = 0; b < BINS; b++) ph[t * 17 + b] = 0;

    float pm = (lane < 16) ? statmin[g * 16 + lane] : 1e30f;
    float px = (lane < 16) ? statmax[g * 16 + lane] : -1e30f;
    for (int o = 8; o; o >>= 1) {
        pm = fminf(pm, __shfl_down(pm, o));
        px = fmaxf(px, __shfl_down(px, o));
    }
    float vmin = sigm(__shfl(pm, 0));
    float vmax = sigm(__shfl(px, 0));
    float width = (vmax - vmin) / (float)BINS;
    float inv = 1.0f / (width > 0.f ? width : 1.0f);

    int half = lane >> 5, r = lane & 31;
    const bf* Ap = f1 + ((size_t)g * NPG + mt * 32 + r) * F3 + half * 8;
    sv8 a0 = *(const sv8*)(Ap +  0);
    sv8 a1 = *(const sv8*)(Ap + 16);
    sv8 a2 = *(const sv8*)(Ap + 32);
    sv8 a3 = *(const sv8*)(Ap + 48);
#pragma unroll
    for (int j = 0; j < 4; j++) {
        int nt = j * 4 + wave;
        const bf* Bp = f2 + ((size_t)g * NPG + nt * 32 + r) * F3 + half * 8;
        fv16 acc;
#pragma unroll
        for (int i = 0; i < 16; i++) acc[i] = 0.f;
        acc = __builtin_amdgcn_mfma_f32_32x32x16_bf16(a0, *(const sv8*)(Bp +  0), acc, 0, 0, 0);
        acc = __builtin_amdgcn_mfma_f32_32x32x16_bf16(a1, *(const sv8*)(Bp + 16), acc, 0, 0, 0);
        acc = __builtin_amdgcn_mfma_f32_32x32x16_bf16(a2, *(const sv8*)(Bp + 32), acc, 0, 0, 0);
        acc = __builtin_amdgcn_mfma_f32_32x32x16_bf16(a3, *(const sv8*)(Bp + 48), acc, 0, 0, 0);
#pragma unroll
        for (int i = 0; i < 16; i++) {
            float v = sigm(acc[i]);
            int bi = (int)floorf((v - vmin) * inv);
            bi = bi < 0 ? 0 : (bi > BINS - 1 ? BINS - 1 : bi);
            ph[t * 17 + bi] += 1;
        }
    }
    __syncthreads();
    {
        int grp = t >> 4, bin = t & 15;
        int s = 0;
#pragma unroll
        for (int j = 0; j < 16; j++) s += ph[(grp * 16 + j) * 17 + bin];
        pr[t] = s;
    }
    __syncthreads();
    if (t < BINS) {
        int tot = 0;
#pragma unroll
        for (int j = 0; j < 16; j++) tot += pr[j * 16 + t];
        hist_p[((size_t)g * 16 + mt) * BINS + t] = tot;
    }
}

// ---------------- attention pool (batched over sides via blockIdx.y) ----------------
__global__ __launch_bounds__(256) void pool_k(const bf* __restrict__ f1, const bf* __restrict__ f2,
                                              const float* __restrict__ wbase,
                                              float* __restrict__ outbase, float scale) {
    int side = blockIdx.y;
    const bf* x = side ? f2 : f1;
    const float* w = wbase ? wbase + (size_t)side * NTOT : nullptr;
    float* out = outbase + (size_t)side * BGR * F3;
    int b = blockIdx.x, t = threadIdx.x;
    int f = t & 63, gq = t >> 6;
    float acc = 0.f;
    for (int r = gq; r < NPG; r += 4) {
        int n = b * NPG + r;
        float c = w ? w[n] : 1.0f;
        acc += c * b2f(x[(size_t)n * F3 + f]);
    }
    __shared__ float red[256];
    red[t] = acc;
    __syncthreads();
    if (gq == 0) {
        float s = red[f] + red[64 + f] + red[128 + f] + red[192 + f];
        out[b * F3 + f] = s * scale;
    }
}

__global__ void ctx_k(const float* __restrict__ meanb, const float* __restrict__ Watt, float* __restrict__ ctxb) {
    int side = blockIdx.y;
    const float* mean = meanb + (size_t)side * BGR * F3;
    float* ctx = ctxb + (size_t)side * BGR * F3;
    int b = blockIdx.x, j = threadIdx.x;  // 64 threads
    float acc = 0.f;
#pragma unroll 8
    for (int i = 0; i < F3; i++) acc += mean[b * F3 + i] * Watt[i * F3 + j];
    ctx[b * F3 + j] = tanhf(acc);
}

__global__ __launch_bounds__(256) void coef_k(const bf* __restrict__ f1, const bf* __restrict__ f2,
                                              const float* __restrict__ ctxb, float* __restrict__ coefb) {
    int side = blockIdx.y;
    const bf* x = side ? f2 : f1;
    const float* ctx = ctxb + (size_t)side * BGR * F3;
    float* coef = coefb + (size_t)side * NTOT;
    int t = blockIdx.x * 256 + threadIdx.x;
    int n = t >> 6;
    int f = t & 63;
    int b = n >> 9;  // N = 512
    float v = b2f(x[(size_t)n * F3 + f]) * ctx[b * F3 + f];
    for (int o = 32; o; o >>= 1) v += __shfl_down(v, o);
    if (f == 0) coef[n] = sigm(v);
}

// ---------------- tensor network + tail MLP ----------------
__global__ __launch_bounds__(256) void final_k(const float* __restrict__ pools,
                                               const float* __restrict__ Wt, const float* __restrict__ Wtb,
                                               const float* __restrict__ tb, const int* __restrict__ hist_p,
                                               const float* __restrict__ W1, const float* __restrict__ b1,
                                               const float* __restrict__ Ws, const float* __restrict__ bs,
                                               float* __restrict__ out) {
    const float* p1 = pools;
    const float* p2 = pools + (size_t)BGR * F3;
    int b = blockIdx.x, t = threadIdx.x;
    __shared__ float cat[128];
    __shared__ float sacc[256];
    __shared__ float feat[32];
    __shared__ float hb[32];
    if (t < 64) cat[t] = p1[b * F3 + t];
    else if (t < 128) cat[t] = p2[b * F3 + (t - 64)];
    __syncthreads();
    int k = t & 15, c = t >> 4;
    float acc = 0.f;
    for (int q = 0; q < 256; q++) {
        int ij = c * 256 + q;
        int i = ij >> 6, j = ij & 63;
        acc += cat[i] * cat[64 + j] * Wt[ij * KT + k];
    }
    sacc[t] = acc;
    __syncthreads();
    if (t < KT) {
        float sc = 0.f;
        for (int c2 = 0; c2 < 16; c2++) sc += sacc[c2 * 16 + t];
        float bt = 0.f;
        for (int i = 0; i < 128; i++) bt += cat[i] * Wtb[t * 128 + i];
        float tv = sc + bt + tb[t];
        feat[t] = tv > 0.f ? tv : 0.f;
        int hsum = 0;
#pragma unroll
        for (int j = 0; j < 16; j++) hsum += hist_p[((size_t)b * 16 + j) * BINS + t];
        feat[KT + t] = (float)hsum * (1.0f / (float)(NPG * NPG));
    }
    __syncthreads();
    if (t < BN) {
        float a = 0.f;
        for (int i = 0; i < KT + BINS; i++) a += feat[i] * W1[i * BN + t];
        a += b1[t];
        hb[t] = a > 0.f ? a : 0.f;
    }
    __syncthreads();
    if (t == 0) {
        float s = bs[0];
        for (int j = 0; j < BN; j++) s += hb[j] * Ws[j];
        out[b] = sigm(s);
    }
}

// ---------------- launch ----------------
extern "C" void kernel_launch(void* const* d_in, const int* in_sizes, int n_in,
                              void* d_out, int out_size, void* d_ws, size_t ws_size,
                              hipStream_t stream) {
    const float* x1   = (const float*)d_in[0];
    const float* x2   = (const float*)d_in[1];
    const int*   ei1  = (const int*)d_in[2];
    const int*   ei2  = (const int*)d_in[3];
    const float* Wc1  = (const float*)d_in[6];
    const float* bc1  = (const float*)d_in[7];
    const float* Wc2  = (const float*)d_in[8];
    const float* bc2  = (const float*)d_in[9];
    const float* Wc3  = (const float*)d_in[10];
    const float* bc3  = (const float*)d_in[11];
    const float* Watt = (const float*)d_in[12];
    const float* Wt   = (const float*)d_in[13];
    const float* Wtb  = (const float*)d_in[14];
    const float* tb   = (const float*)d_in[15];
    const float* W1   = (const float*)d_in[16];
    const float* b1   = (const float*)d_in[17];
    const float* Ws   = (const float*)d_in[18];
    const float* bs   = (const float*)d_in[19];
    float* out = (float*)d_out;

    // ---- workspace layout (~55 MB) ----
    char* wsb = (char*)d_ws;
    size_t o = 0;
    auto alloc = [&](size_t bytes) -> void* {
        void* p = wsb + o;
        o = (o + bytes + 255) & ~(size_t)255;
        return p;
    };
    bf* f1b  = (bf*)alloc((size_t)NTOT * F3 * 2);     //  8 MB
    bf* f2b  = (bf*)alloc((size_t)NTOT * F3 * 2);     //  8 MB
    bf* X    = (bf*)alloc((size_t)NTOT * F1 * 2);     // 16 MB
    bf* Y    = (bf*)alloc((size_t)NTOT * F2 * 2);     // 12 MB
    int* off   = (int*)alloc((size_t)2 * (NTOT + 1) * 4);
    int* csrc  = (int*)alloc((size_t)2 * NEDGE * 4);  // 4 MB
    float* cnorm = (float*)alloc((size_t)2 * NEDGE * 4); // 4 MB
    int* deg   = (int*)alloc((size_t)2 * NTOT * 4);
    float* dinv = (float*)alloc((size_t)2 * NTOT * 4);
    int* cur   = (int*)alloc((size_t)2 * NTOT * 4);
    int* bsum  = (int*)alloc(2048);
    float* statmin = (float*)alloc((size_t)BGR * 16 * 4);
    float* statmax = (float*)alloc((size_t)BGR * 16 * 4);
    int* hist_p = (int*)alloc((size_t)BGR * 16 * BINS * 4);  // 128 KB, block-owned
    float* mean = (float*)alloc((size_t)2 * BGR * F3 * 4);
    float* ctx  = (float*)alloc((size_t)2 * BGR * F3 * 4);
    float* pools = (float*)alloc((size_t)2 * BGR * F3 * 4);
    float* coef = (float*)alloc((size_t)2 * NTOT * 4);
    bf* wt1 = (bf*)alloc((size_t)NL * F1 * 2);   // Wt1[F1][NL]
    bf* wt2 = (bf*)alloc((size_t)F1 * F2 * 2);   // Wt2[F2][F1]
    bf* wt3 = (bf*)alloc((size_t)F2 * F3 * 2);   // Wt3[F3][F2]
    (void)ws_size; (void)in_sizes; (void)n_in; (void)out_size;

    // inits (ws is re-poisoned before every call); stat/hist need none (owner-written)
    fillz_k<<<(2 * NTOT) / 256, 256, 0, stream>>>((unsigned*)deg, 2 * NTOT);
    fillz_k<<<(2 * NTOT) / 256, 256, 0, stream>>>((unsigned*)cur, 2 * NTOT);

    // weight transpose+convert (tiny)
    wconv_k<<<(NL * F1 + 255) / 256, 256, 0, stream>>>(Wc1, wt1, NL, F1);
    wconv_k<<<(F1 * F2 + 255) / 256, 256, 0, stream>>>(Wc2, wt2, F1, F2);
    wconv_k<<<(F2 * F3 + 255) / 256, 256, 0, stream>>>(Wc3, wt3, F2, F3);

    // ---- CSR build, both sides batched ----
    deg_k<<<dim3(NEDGE / 256, 2), 256, 0, stream>>>(ei1, ei2, deg);
    dinv_k<<<dim3(NTOT / 256, 2), 256, 0, stream>>>(deg, dinv);
    scan1_k<<<dim3(NTOT / 256, 2), 256, 0, stream>>>(deg, off, bsum);
    scan2_k<<<2, 256, 0, stream>>>(bsum);
    scan3_k<<<dim3(NTOT / 256, 2), 256, 0, stream>>>(off, bsum);
    scatter_k<<<dim3(NEDGE / 256, 2), 256, 0, stream>>>(ei1, ei2, off, cur, dinv, csrc, cnorm);

    // ---- GCN stack (sequential sides; X/Y shared) ----
    const float* xs[2] = {x1, x2};
    bf* fs[2] = {f1b, f2b};
    for (int s = 0; s < 2; s++) {
        const int* offs = off + s * (NTOT + 1);
        const int* cs   = csrc + (size_t)s * NEDGE;
        const float* cn = cnorm + (size_t)s * NEDGE;
        const float* dv = dinv + (size_t)s * NTOT;
        // z1 = A_hat x (fp32 in, NL wide) -> Y
        agg_k<NL, 0, 0, 1><<<(NTOT * (NL / 4)) / 256, 256, 0, stream>>>(xs[s], nullptr, offs, cs, cn, dv, Y);
        // h1 = relu(z1 Wc1 + bc1) -> X   [A_hat(xW) == (A_hat x)W]
        gemmm_k<NL, F1, 1, 1><<<NTOT / 128, 256, 0, stream>>>(Y, wt1, bc1, X);
        // t2 = h1 Wc2 -> Y
        gemmm_k<F1, F2, 0, 0><<<NTOT / 128, 256, 0, stream>>>(X, wt2, nullptr, Y);
        // h2 = relu(A_hat t2 + bc2) -> X
        agg_k<F2, 1, 1, 0><<<(NTOT * (F2 / 4)) / 256, 256, 0, stream>>>(Y, bc2, offs, cs, cn, dv, X);
        // t3 = h2 Wc3 -> Y
        gemmm_k<F2, F3, 0, 0><<<NTOT / 128, 256, 0, stream>>>(X, wt3, nullptr, Y);
        // f = A_hat t3 + bc3 -> fs[s]
        agg_k<F3, 1, 0, 0><<<(NTOT * (F3 / 4)) / 256, 256, 0, stream>>>(Y, bc3, offs, cs, cn, dv, fs[s]);
    }

    // ---- MFMA histogram similarity: per-stripe minmax partials, then binning ----
    simm_k<<<dim3(16, BGR), 256, 0, stream>>>(f1b, f2b, statmin, statmax);
    simh_k<<<dim3(16, BGR), 256, 0, stream>>>(f1b, f2b, statmin, statmax, hist_p);

    // ---- attention pooling, both sides batched ----
    pool_k<<<dim3(BGR, 2), 256, 0, stream>>>(f1b, f2b, nullptr, mean, 1.0f / (float)NPG);
    ctx_k<<<dim3(BGR, 2), 64, 0, stream>>>(mean, Watt, ctx);
    coef_k<<<dim3((NTOT * 64) / 256, 2), 256, 0, stream>>>(f1b, f2b, ctx, coef);
    pool_k<<<dim3(BGR, 2), 256, 0, stream>>>(f1b, f2b, coef, pools, 1.0f);

    // ---- tensor network + MLP tail ----
    final_k<<<BGR, 256, 0, stream>>>(pools, Wt, Wtb, tb, hist_p, W1, b1, Ws, bs, out);
}

// Round 6
// 478.359 us; speedup vs baseline: 2.4788x; 1.1822x over previous
//
#include <hip/hip_runtime.h>
#include <math.h>

#define NTOT  65536
#define NEDGE 524288
#define BGR   128
#define NPG   512
#define NL    32
#define F1    128
#define F2    96
#define F3    64
#define KT    16
#define BINS  16
#define BN    32
#define GCAP  6144   // per-graph edge bucket capacity (mean 4096, +32 sigma)

typedef unsigned short bf;
typedef __attribute__((ext_vector_type(8))) short sv8;    // 8 bf16 fragment (4 VGPRs)
typedef __attribute__((ext_vector_type(16))) float fv16;  // 32x32 mfma accumulator

// ---------------- helpers ----------------
__device__ __forceinline__ float b2f(bf v) { return __uint_as_float(((unsigned)v) << 16); }
__device__ __forceinline__ bf f2b(float f) {
    unsigned u = __float_as_uint(f);
    return (bf)((u + 0x7FFF + ((u >> 16) & 1)) >> 16);  // RNE
}
__device__ __forceinline__ float sigm(float x) { return 1.f / (1.f + expf(-x)); }

// ---------------- init ----------------
__global__ __launch_bounds__(256) void fillz_k(unsigned* __restrict__ p, int n) {
    int i = blockIdx.x * 256 + threadIdx.x;
    if (i < n) p[i] = 0u;
}

// all three weights transposed+converted in one kernel
__global__ __launch_bounds__(256) void wconv_k(const float* __restrict__ W1, const float* __restrict__ W2,
                                               const float* __restrict__ W3,
                                               bf* __restrict__ T1, bf* __restrict__ T2, bf* __restrict__ T3) {
    int i = blockIdx.x * 256 + threadIdx.x;
    if (i < NL * F1) {
        int co = i >> 5, ci = i & 31;                 // cin=32
        T1[i] = f2b(W1[ci * F1 + co]);
    } else if (i < NL * F1 + F1 * F2) {
        int i2 = i - NL * F1;
        int co = i2 >> 7, ci = i2 & 127;              // cin=128
        T2[i2] = f2b(W2[ci * F2 + co]);
    } else if (i < NL * F1 + F1 * F2 + F2 * F3) {
        int i3 = i - NL * F1 - F1 * F2;
        int co = i3 / 96, ci = i3 - co * 96;          // cin=96
        T3[i3] = f2b(W3[ci * F3 + co]);
    }
}

// ---------------- CSR build: graph-bucket then per-graph sort ----------------
// Phase A: bin edges by graph. One packed u32 per edge: (src<<9)|dst_local.
__global__ __launch_bounds__(256) void bucket_k(const int* __restrict__ ei1, const int* __restrict__ ei2,
                                                int* __restrict__ gcount, unsigned* __restrict__ bucket) {
    int side = blockIdx.y;
    const int* src = side ? ei2 : ei1;
    const int* dst = src + NEDGE;
    __shared__ int bc[128], bbase[128], bcur[128];
    int t = threadIdx.x;
    if (t < 128) { bc[t] = 0; bcur[t] = 0; }
    __syncthreads();
    int e0 = blockIdx.x * 1024;
    unsigned lp[4];
    int lg[4];
#pragma unroll
    for (int i = 0; i < 4; i++) {
        int e = e0 + i * 256 + t;
        int s = src[e], d = dst[e];
        int g = d >> 9;
        lp[i] = ((unsigned)s << 9) | (unsigned)(d & 511);
        lg[i] = g;
        atomicAdd(&bc[g], 1);
    }
    __syncthreads();
    if (t < 128 && bc[t] > 0) bbase[t] = atomicAdd(&gcount[side * 128 + t], bc[t]);
    __syncthreads();
#pragma unroll
    for (int i = 0; i < 4; i++) {
        int g = lg[i];
        int pos = bbase[g] + atomicAdd(&bcur[g], 1);
        if (pos < GCAP) bucket[((size_t)side * 128 + g) * GCAP + pos] = lp[i];
    }
}

// exclusive scan of per-graph counts -> global edge base (per side region)
__global__ void gscan_k(const int* __restrict__ gcount, int* __restrict__ gbase) {
    __shared__ int s[256];
    int t = threadIdx.x;
    int x = gcount[t];
    s[t] = x;
    __syncthreads();
    for (int o = 1; o < 128; o <<= 1) {
        int v = ((t & 127) >= o) ? s[t - o] : 0;
        __syncthreads();
        s[t] += v;
        __syncthreads();
    }
    gbase[t] = (t >> 7) * NEDGE + s[t] - x;
}

// Phase B: one block per graph. Count/scan/place in LDS; all global writes land
// in the block-owned contiguous region -> no write amplification, no global atomics.
__global__ __launch_bounds__(256) void csr_k(const unsigned* __restrict__ bucket, const int* __restrict__ gcount,
                                             const int* __restrict__ gbase, int* __restrict__ off,
                                             float* __restrict__ dinv, int2* __restrict__ ecsr) {
    int side = blockIdx.y, g = blockIdx.x, t = threadIdx.x;
    __shared__ int ncnt[512];
    __shared__ int c2[256];
    __shared__ int cur[512];
    __shared__ float dloc[512];
    ncnt[t] = 0; ncnt[t + 256] = 0;
    __syncthreads();
    int cnt = gcount[side * 128 + g];
    cnt = cnt < GCAP ? cnt : GCAP;
    int base = gbase[side * 128 + g];
    const unsigned* bk = bucket + ((size_t)side * 128 + g) * GCAP;
    for (int i = t; i < cnt; i += 256) atomicAdd(&ncnt[bk[i] & 511], 1);
    __syncthreads();
    int e0 = ncnt[2 * t], e1 = ncnt[2 * t + 1];
    c2[t] = e0 + e1;
    __syncthreads();
    for (int o = 1; o < 256; o <<= 1) {
        int v = (t >= o) ? c2[t - o] : 0;
        __syncthreads();
        c2[t] += v;
        __syncthreads();
    }
    int ex = c2[t] - (e0 + e1);
    cur[2 * t] = ex;
    cur[2 * t + 1] = ex + e0;
    float d0 = rsqrtf((float)e0 + 1.f), d1 = rsqrtf((float)e1 + 1.f);
    dloc[2 * t] = d0; dloc[2 * t + 1] = d1;
    int node0 = g * NPG + 2 * t;
    int* offs = off + side * (NTOT + 1);
    offs[node0] = base + ex;
    offs[node0 + 1] = base + ex + e0;
    *(float2*)(dinv + (size_t)side * NTOT + node0) = make_float2(d0, d1);
    if (g == BGR - 1 && t == 0) offs[NTOT] = (side + 1) * NEDGE;
    __syncthreads();
    for (int i = t; i < cnt; i += 256) {
        unsigned p = bk[i];
        int dl = p & 511;
        int s = p >> 9;
        int pos = atomicAdd(&cur[dl], 1);
        float nm = dloc[s & 511] * dloc[dl];
        ecsr[base + pos] = make_int2(s, __float_as_int(nm));
    }
}

// ---------------- MFMA GEMM: out[NT x COUT](bf16) = X[NT x CIN](bf16) @ W ----------------
template <int CIN, int COUT, int BIAS, int RELU>
__global__ __launch_bounds__(256) void gemmm_k(const bf* __restrict__ X, const bf* __restrict__ Wt,
                                               const float* __restrict__ bias, bf* __restrict__ out) {
    int wave = threadIdx.x >> 6, lane = threadIdx.x & 63;
    int half = lane >> 5, r = lane & 31;
    int row0 = blockIdx.x * 128 + wave * 32;
    const bf* Ap = X + (size_t)(row0 + r) * CIN + half * 8;
    sv8 a[CIN / 16];
#pragma unroll
    for (int k = 0; k < CIN / 16; k++) a[k] = *(const sv8*)(Ap + k * 16);
#pragma unroll
    for (int nt = 0; nt < COUT / 32; nt++) {
        const bf* Bp = Wt + (size_t)(nt * 32 + r) * CIN + half * 8;
        fv16 acc;
#pragma unroll
        for (int i = 0; i < 16; i++) acc[i] = 0.f;
#pragma unroll
        for (int k = 0; k < CIN / 16; k++)
            acc = __builtin_amdgcn_mfma_f32_32x32x16_bf16(a[k], *(const sv8*)(Bp + k * 16), acc, 0, 0, 0);
        float bv = BIAS ? bias[nt * 32 + r] : 0.f;
#pragma unroll
        for (int i = 0; i < 16; i++) {
            int rr = (i & 3) + 8 * (i >> 2) + 4 * half;
            float v = acc[i] + bv;
            if (RELU) v = fmaxf(v, 0.f);
            out[(size_t)(row0 + rr) * COUT + nt * 32 + r] = f2b(v);
        }
    }
}

// ---------------- GCN aggregation (gather via CSR, packed {src,norm} edges) ----------------
template <int C, int BIAS, int RELU, int FIN32>
__global__ __launch_bounds__(256) void agg_k(const void* __restrict__ hin_, const float* __restrict__ bias,
                                             const int* __restrict__ off, const int2* __restrict__ ecsr,
                                             const float* __restrict__ dinv, bf* __restrict__ out) {
    constexpr int C4 = C / 4;
    int t = blockIdx.x * 256 + threadIdx.x;
    int node = t / C4;
    int c = (t % C4) * 4;
    float d = dinv[node];
    float sc = d * d;
    float ax, ay, az, aw;
    if (FIN32) {
        const float* hin = (const float*)hin_;
        float4 h = *(const float4*)(hin + (size_t)node * C + c);
        ax = h.x * sc; ay = h.y * sc; az = h.z * sc; aw = h.w * sc;
    } else {
        const bf* hin = (const bf*)hin_;
        ushort4 h = *(const ushort4*)(hin + (size_t)node * C + c);
        ax = b2f(h.x) * sc; ay = b2f(h.y) * sc; az = b2f(h.z) * sc; aw = b2f(h.w) * sc;
    }
    int e0 = off[node], e1 = off[node + 1];
    for (int j = e0; j < e1; j++) {
        int2 en = ecsr[j];
        int s = en.x;
        float w = __int_as_float(en.y);
        if (FIN32) {
            const float* hin = (const float*)hin_;
            float4 hs = *(const float4*)(hin + (size_t)s * C + c);
            ax += w * hs.x; ay += w * hs.y; az += w * hs.z; aw += w * hs.w;
        } else {
            const bf* hin = (const bf*)hin_;
            ushort4 hs = *(const ushort4*)(hin + (size_t)s * C + c);
            ax += w * b2f(hs.x); ay += w * b2f(hs.y); az += w * b2f(hs.z); aw += w * b2f(hs.w);
        }
    }
    if (BIAS) {
        float4 bv = *(const float4*)(bias + c);
        ax += bv.x; ay += bv.y; az += bv.z; aw += bv.w;
    }
    if (RELU) {
        ax = fmaxf(ax, 0.f); ay = fmaxf(ay, 0.f); az = fmaxf(az, 0.f); aw = fmaxf(aw, 0.f);
    }
    ushort4 o;
    o.x = f2b(ax); o.y = f2b(ay); o.z = f2b(az); o.w = f2b(aw);
    *(ushort4*)(out + (size_t)node * C + c) = o;
}

// ---------------- MFMA similarity ----------------
__global__ __launch_bounds__(256) void simm_k(const bf* __restrict__ f1, const bf* __restrict__ f2,
                                              float* __restrict__ statmin, float* __restrict__ statmax) {
    int g = blockIdx.y, mt = blockIdx.x;
    int t = threadIdx.x, wave = t >> 6, lane = t & 63;
    int half = lane >> 5, r = lane & 31;
    const bf* Ap = f1 + ((size_t)g * NPG + mt * 32 + r) * F3 + half * 8;
    sv8 a0 = *(const sv8*)(Ap +  0);
    sv8 a1 = *(const sv8*)(Ap + 16);
    sv8 a2 = *(const sv8*)(Ap + 32);
    sv8 a3 = *(const sv8*)(Ap + 48);
    float mn = 1e30f, mx = -1e30f;
#pragma unroll
    for (int j = 0; j < 4; j++) {
        int nt = j * 4 + wave;
        const bf* Bp = f2 + ((size_t)g * NPG + nt * 32 + r) * F3 + half * 8;
        fv16 acc;
#pragma unroll
        for (int i = 0; i < 16; i++) acc[i] = 0.f;
        acc = __builtin_amdgcn_mfma_f32_32x32x16_bf16(a0, *(const sv8*)(Bp +  0), acc, 0, 0, 0);
        acc = __builtin_amdgcn_mfma_f32_32x32x16_bf16(a1, *(const sv8*)(Bp + 16), acc, 0, 0, 0);
        acc = __builtin_amdgcn_mfma_f32_32x32x16_bf16(a2, *(const sv8*)(Bp + 32), acc, 0, 0, 0);
        acc = __builtin_amdgcn_mfma_f32_32x32x16_bf16(a3, *(const sv8*)(Bp + 48), acc, 0, 0, 0);
#pragma unroll
        for (int i = 0; i < 16; i++) {
            mn = fminf(mn, acc[i]);
            mx = fmaxf(mx, acc[i]);
        }
    }
    for (int o = 32; o; o >>= 1) {
        mn = fminf(mn, __shfl_down(mn, o));
        mx = fmaxf(mx, __shfl_down(mx, o));
    }
    __shared__ float smn[4], smx[4];
    if (lane == 0) { smn[wave] = mn; smx[wave] = mx; }
    __syncthreads();
    if (t == 0) {
        statmin[g * 16 + mt] = fminf(fminf(smn[0], smn[1]), fminf(smn[2], smn[3]));
        statmax[g * 16 + mt] = fmaxf(fmaxf(smx[0], smx[1]), fmaxf(smx[2], smx[3]));
    }
}

__global__ __launch_bounds__(256) void simh_k(const bf* __restrict__ f1, const bf* __restrict__ f2,
                                              const float* __restrict__ statmin, const float* __restrict__ statmax,
                                              int* __restrict__ hist_p) {
    __shared__ int ph[256 * 17];   // per-THREAD private hist, stride 17 (bank-spread)
    __shared__ int pr[256];
    int g = blockIdx.y, mt = blockIdx.x;
    int t = threadIdx.x, wave = t >> 6, lane = t & 63;
#pragma unroll
    for (int b = 0; b < BINS; b++) ph[t * 17 + b] = 0;

    float pm = (lane < 16) ? statmin[g * 16 + lane] : 1e30f;
    float px = (lane < 16) ? statmax[g * 16 + lane] : -1e30f;
    for (int o = 8; o; o >>= 1) {
        pm = fminf(pm, __shfl_down(pm, o));
        px = fmaxf(px, __shfl_down(px, o));
    }
    float vmin = sigm(__shfl(pm, 0));
    float vmax = sigm(__shfl(px, 0));
    float width = (vmax - vmin) / (float)BINS;
    float inv = 1.0f / (width > 0.f ? width : 1.0f);

    int half = lane >> 5, r = lane & 31;
    const bf* Ap = f1 + ((size_t)g * NPG + mt * 32 + r) * F3 + half * 8;
    sv8 a0 = *(const sv8*)(Ap +  0);
    sv8 a1 = *(const sv8*)(Ap + 16);
    sv8 a2 = *(const sv8*)(Ap + 32);
    sv8 a3 = *(const sv8*)(Ap + 48);
#pragma unroll
    for (int j = 0; j < 4; j++) {
        int nt = j * 4 + wave;
        const bf* Bp = f2 + ((size_t)g * NPG + nt * 32 + r) * F3 + half * 8;
        fv16 acc;
#pragma unroll
        for (int i = 0; i < 16; i++) acc[i] = 0.f;
        acc = __builtin_amdgcn_mfma_f32_32x32x16_bf16(a0, *(const sv8*)(Bp +  0), acc, 0, 0, 0);
        acc = __builtin_amdgcn_mfma_f32_32x32x16_bf16(a1, *(const sv8*)(Bp + 16), acc, 0, 0, 0);
        acc = __builtin_amdgcn_mfma_f32_32x32x16_bf16(a2, *(const sv8*)(Bp + 32), acc, 0, 0, 0);
        acc = __builtin_amdgcn_mfma_f32_32x32x16_bf16(a3, *(const sv8*)(Bp + 48), acc, 0, 0, 0);
#pragma unroll
        for (int i = 0; i < 16; i++) {
            float v = sigm(acc[i]);
            int bi = (int)floorf((v - vmin) * inv);
            bi = bi < 0 ? 0 : (bi > BINS - 1 ? BINS - 1 : bi);
            ph[t * 17 + bi] += 1;
        }
    }
    __syncthreads();
    {
        int grp = t >> 4, bin = t & 15;
        int s = 0;
#pragma unroll
        for (int j = 0; j < 16; j++) s += ph[(grp * 16 + j) * 17 + bin];
        pr[t] = s;
    }
    __syncthreads();
    if (t < BINS) {
        int tot = 0;
#pragma unroll
        for (int j = 0; j < 16; j++) tot += pr[j * 16 + t];
        hist_p[((size_t)g * 16 + mt) * BINS + t] = tot;
    }
}

// ---------------- fused attention pool: mean -> ctx -> coef -> weighted sum ----------------
// one block per (graph, side); f rows stay in registers between coef dot and pooling
__global__ __launch_bounds__(256) void attn_k(const bf* __restrict__ f1, const bf* __restrict__ f2,
                                              const float* __restrict__ Watt, float* __restrict__ pools) {
    int side = blockIdx.y, g = blockIdx.x;
    const bf* x = (side ? f2 : f1) + (size_t)g * NPG * F3;
    int t = threadIdx.x, wave = t >> 6, f = t & 63;
    __shared__ float red[256];
    __shared__ float meanl[64];
    __shared__ float ctxl[64];
    // mean over 512 nodes
    float m = 0.f;
    for (int n = wave; n < NPG; n += 4) m += b2f(x[(size_t)n * F3 + f]);
    red[t] = m;
    __syncthreads();
    if (t < 64) meanl[t] = (red[t] + red[64 + t] + red[128 + t] + red[192 + t]) * (1.0f / (float)NPG);
    __syncthreads();
    // ctx = tanh(mean @ Watt)
    if (t < 64) {
        float acc = 0.f;
#pragma unroll 8
        for (int i = 0; i < F3; i++) acc += meanl[i] * Watt[i * F3 + t];
        ctxl[t] = tanhf(acc);
    }
    __syncthreads();
    // coef + weighted pool, rows in registers
    float cx = ctxl[f];
    float acc = 0.f;
    for (int n = wave; n < NPG; n += 4) {
        float v = b2f(x[(size_t)n * F3 + f]);
        float d = v * cx;
#pragma unroll
        for (int o = 1; o < 64; o <<= 1) d += __shfl_xor(d, o);
        acc += sigm(d) * v;
    }
    red[t] = acc;
    __syncthreads();
    if (t < 64) pools[((size_t)side * BGR + g) * F3 + t] = red[t] + red[64 + t] + red[128 + t] + red[192 + t];
}

// ---------------- tensor network + tail MLP ----------------
__global__ __launch_bounds__(256) void final_k(const float* __restrict__ pools,
                                               const float* __restrict__ Wt, const float* __restrict__ Wtb,
                                               const float* __restrict__ tb, const int* __restrict__ hist_p,
                                               const float* __restrict__ W1, const float* __restrict__ b1,
                                               const float* __restrict__ Ws, const float* __restrict__ bs,
                                               float* __restrict__ out) {
    const float* p1 = pools;
    const float* p2 = pools + (size_t)BGR * F3;
    int b = blockIdx.x, t = threadIdx.x;
    __shared__ float cat[128];
    __shared__ float sacc[256];
    __shared__ float feat[32];
    __shared__ float hb[32];
    if (t < 64) cat[t] = p1[b * F3 + t];
    else if (t < 128) cat[t] = p2[b * F3 + (t - 64)];
    __syncthreads();
    int k = t & 15, c = t >> 4;
    float acc = 0.f;
    for (int q = 0; q < 256; q++) {
        int ij = c * 256 + q;
        int i = ij >> 6, j = ij & 63;
        acc += cat[i] * cat[64 + j] * Wt[ij * KT + k];
    }
    sacc[t] = acc;
    __syncthreads();
    if (t < KT) {
        float sc = 0.f;
        for (int c2 = 0; c2 < 16; c2++) sc += sacc[c2 * 16 + t];
        float bt = 0.f;
        for (int i = 0; i < 128; i++) bt += cat[i] * Wtb[t * 128 + i];
        float tv = sc + bt + tb[t];
        feat[t] = tv > 0.f ? tv : 0.f;
        int hsum = 0;
#pragma unroll
        for (int j = 0; j < 16; j++) hsum += hist_p[((size_t)b * 16 + j) * BINS + t];
        feat[KT + t] = (float)hsum * (1.0f / (float)(NPG * NPG));
    }
    __syncthreads();
    if (t < BN) {
        float a = 0.f;
        for (int i = 0; i < KT + BINS; i++) a += feat[i] * W1[i * BN + t];
        a += b1[t];
        hb[t] = a > 0.f ? a : 0.f;
    }
    __syncthreads();
    if (t == 0) {
        float s = bs[0];
        for (int j = 0; j < BN; j++) s += hb[j] * Ws[j];
        out[b] = sigm(s);
    }
}

// ---------------- launch ----------------
extern "C" void kernel_launch(void* const* d_in, const int* in_sizes, int n_in,
                              void* d_out, int out_size, void* d_ws, size_t ws_size,
                              hipStream_t stream) {
    const float* x1   = (const float*)d_in[0];
    const float* x2   = (const float*)d_in[1];
    const int*   ei1  = (const int*)d_in[2];
    const int*   ei2  = (const int*)d_in[3];
    const float* Wc1  = (const float*)d_in[6];
    const float* bc1  = (const float*)d_in[7];
    const float* Wc2  = (const float*)d_in[8];
    const float* bc2  = (const float*)d_in[9];
    const float* Wc3  = (const float*)d_in[10];
    const float* bc3  = (const float*)d_in[11];
    const float* Watt = (const float*)d_in[12];
    const float* Wt   = (const float*)d_in[13];
    const float* Wtb  = (const float*)d_in[14];
    const float* tb   = (const float*)d_in[15];
    const float* W1   = (const float*)d_in[16];
    const float* b1   = (const float*)d_in[17];
    const float* Ws   = (const float*)d_in[18];
    const float* bs   = (const float*)d_in[19];
    float* out = (float*)d_out;

    // ---- workspace layout (~60 MB) ----
    char* wsb = (char*)d_ws;
    size_t o = 0;
    auto alloc = [&](size_t bytes) -> void* {
        void* p = wsb + o;
        o = (o + bytes + 255) & ~(size_t)255;
        return p;
    };
    bf* f1b  = (bf*)alloc((size_t)NTOT * F3 * 2);     //  8 MB
    bf* f2b  = (bf*)alloc((size_t)NTOT * F3 * 2);     //  8 MB
    bf* X    = (bf*)alloc((size_t)NTOT * F1 * 2);     // 16 MB
    bf* Y    = (bf*)alloc((size_t)NTOT * F2 * 2);     // 12 MB
    int* off   = (int*)alloc((size_t)2 * (NTOT + 1) * 4);
    int2* ecsr = (int2*)alloc((size_t)2 * NEDGE * 8);              // 8 MB packed {src,norm}
    unsigned* bucket = (unsigned*)alloc((size_t)2 * 128 * GCAP * 4); // 6.3 MB
    int* gcount = (int*)alloc(256 * 4);
    int* gbase  = (int*)alloc(256 * 4);
    float* dinv = (float*)alloc((size_t)2 * NTOT * 4);
    float* statmin = (float*)alloc((size_t)BGR * 16 * 4);
    float* statmax = (float*)alloc((size_t)BGR * 16 * 4);
    int* hist_p = (int*)alloc((size_t)BGR * 16 * BINS * 4);
    float* pools = (float*)alloc((size_t)2 * BGR * F3 * 4);
    bf* wt1 = (bf*)alloc((size_t)NL * F1 * 2);   // Wt1[F1][NL]
    bf* wt2 = (bf*)alloc((size_t)F1 * F2 * 2);   // Wt2[F2][F1]
    bf* wt3 = (bf*)alloc((size_t)F2 * F3 * 2);   // Wt3[F3][F2]
    (void)ws_size; (void)in_sizes; (void)n_in; (void)out_size;

    // init: only gcount needs zeroing (everything else owner-written)
    fillz_k<<<1, 256, 0, stream>>>((unsigned*)gcount, 256);
    wconv_k<<<(NL * F1 + F1 * F2 + F2 * F3 + 255) / 256, 256, 0, stream>>>(Wc1, Wc2, Wc3, wt1, wt2, wt3);

    // ---- CSR build: bucket by graph, scan, per-graph sort ----
    bucket_k<<<dim3(NEDGE / 1024, 2), 256, 0, stream>>>(ei1, ei2, gcount, bucket);
    gscan_k<<<1, 256, 0, stream>>>(gcount, gbase);
    csr_k<<<dim3(BGR, 2), 256, 0, stream>>>(bucket, gcount, gbase, off, dinv, ecsr);

    // ---- GCN stack (sequential sides; X/Y shared) ----
    const float* xs[2] = {x1, x2};
    bf* fs[2] = {f1b, f2b};
    for (int s = 0; s < 2; s++) {
        const int* offs = off + s * (NTOT + 1);
        const float* dv = dinv + (size_t)s * NTOT;
        // z1 = A_hat x (fp32 in, NL wide) -> Y
        agg_k<NL, 0, 0, 1><<<(NTOT * (NL / 4)) / 256, 256, 0, stream>>>(xs[s], nullptr, offs, ecsr, dv, Y);
        // h1 = relu(z1 Wc1 + bc1) -> X   [A_hat(xW) == (A_hat x)W]
        gemmm_k<NL, F1, 1, 1><<<NTOT / 128, 256, 0, stream>>>(Y, wt1, bc1, X);
        // t2 = h1 Wc2 -> Y
        gemmm_k<F1, F2, 0, 0><<<NTOT / 128, 256, 0, stream>>>(X, wt2, nullptr, Y);
        // h2 = relu(A_hat t2 + bc2) -> X
        agg_k<F2, 1, 1, 0><<<(NTOT * (F2 / 4)) / 256, 256, 0, stream>>>(Y, bc2, offs, ecsr, dv, X);
        // t3 = h2 Wc3 -> Y
        gemmm_k<F2, F3, 0, 0><<<NTOT / 128, 256, 0, stream>>>(X, wt3, nullptr, Y);
        // f = A_hat t3 + bc3 -> fs[s]
        agg_k<F3, 1, 0, 0><<<(NTOT * (F3 / 4)) / 256, 256, 0, stream>>>(Y, bc3, offs, ecsr, dv, fs[s]);
    }

    // ---- MFMA histogram similarity: per-stripe minmax partials, then binning ----
    simm_k<<<dim3(16, BGR), 256, 0, stream>>>(f1b, f2b, statmin, statmax);
    simh_k<<<dim3(16, BGR), 256, 0, stream>>>(f1b, f2b, statmin, statmax, hist_p);

    // ---- fused attention pooling, both sides ----
    attn_k<<<dim3(BGR, 2), 256, 0, stream>>>(f1b, f2b, Watt, pools);

    // ---- tensor network + MLP tail ----
    final_k<<<BGR, 256, 0, stream>>>(pools, Wt, Wtb, tb, hist_p, W1, b1, Ws, bs, out);
}